// Round 7
// baseline (347.952 us; speedup 1.0000x reference)
//
#include <hip/hip_runtime.h>
#include <hip/hip_bf16.h>

typedef __attribute__((ext_vector_type(4))) float f32x4;
typedef __attribute__((ext_vector_type(8))) __bf16 bf16x8;
typedef __attribute__((ext_vector_type(4))) unsigned int u32x4;

#define EMB 1024
#define NHEAD 16
#define HDIM 64
#define SEQ 2048
#define BATCH 4
#define NTOK 8192

__device__ __forceinline__ unsigned short f2bf(float f) {
    unsigned int u = __builtin_bit_cast(unsigned int, f);
    u = (u + 0x7fffu + ((u >> 16) & 1u)) >> 16;
    return (unsigned short)u;
}

// packed 2x f32->bf16 ; compiler lowers the cast pair to v_cvt_pk_bf16_f32
__device__ __forceinline__ unsigned int cvt2_bf16(float lo, float hi) {
    unsigned short a = __builtin_bit_cast(unsigned short, (__bf16)lo);
    unsigned short b = __builtin_bit_cast(unsigned short, (__bf16)hi);
    return (unsigned int)a | ((unsigned int)b << 16);
}

__device__ __forceinline__ unsigned long long pack_bf4(const f32x4 v) {
    unsigned long long lo = cvt2_bf16(v[0], v[1]);
    unsigned long long hi = cvt2_bf16(v[2], v[3]);
    return lo | (hi << 32);
}

__device__ __forceinline__ void async_copy16(const ushort* g, ushort* l) {
    __builtin_amdgcn_global_load_lds(
        (const __attribute__((address_space(1))) void*)g,
        (__attribute__((address_space(3))) void*)l,
        16, 0, 0);
}

// ---------------- fp32 -> bf16 convert ----------------
__global__ void cvt_f32_bf16(const float4* __restrict__ in, ushort* __restrict__ out, int n4) {
    int i = blockIdx.x * 256 + threadIdx.x;
    if (i < n4) {
        float4 v = in[i];
        ushort4 o;
        o.x = f2bf(v.x); o.y = f2bf(v.y); o.z = f2bf(v.z); o.w = f2bf(v.w);
        ((ushort4*)out)[i] = o;
    }
}

// ================= 128x128-tile GEMM core, BK=64 (r6: halved barrier count) ======
// K-tile staged as two 32-col halves As0/As1 (Bs0/Bs1), each [128][32] with the
// same per-row 16B-chunk XOR swizzle as the verified BK=32 version.
#define GEMM_STAGE64(Asrc, Bsrc, m0, n0, kt)                                      \
    {                                                                             \
        _Pragma("unroll")                                                         \
        for (int j = 0; j < 2; ++j) {                                             \
            int row = wave * 32 + j * 16 + (lane >> 2);                           \
            int kc  = (lane & 3) ^ ((row >> 1) & 3);                              \
            const ushort* asrc = Asrc + (size_t)(m0 + row) * EMB + kt + kc * 8;   \
            const ushort* bsrc = Bsrc + (size_t)(n0 + row) * EMB + kt + kc * 8;   \
            async_copy16(asrc,      As0 + (wave * 32 + j * 16) * 32);             \
            async_copy16(asrc + 32, As1 + (wave * 32 + j * 16) * 32);             \
            async_copy16(bsrc,      Bs0 + (wave * 32 + j * 16) * 32);             \
            async_copy16(bsrc + 32, Bs1 + (wave * 32 + j * 16) * 32);             \
        }                                                                         \
    }

#define GEMM_BODY64(Asrc, Bsrc, m0, n0)                                           \
    f32x4 acc[4][4] = {};                                                         \
    for (int kt = 0; kt < EMB; kt += 64) {                                        \
        GEMM_STAGE64(Asrc, Bsrc, m0, n0, kt)                                      \
        __syncthreads();                                                          \
        _Pragma("unroll")                                                         \
        for (int hf = 0; hf < 2; ++hf) {                                          \
            const ushort* Ah = hf ? As1 : As0;                                    \
            const ushort* Bh = hf ? Bs1 : Bs0;                                    \
            bf16x8 a[4], b[4];                                                    \
            _Pragma("unroll")                                                     \
            for (int i = 0; i < 4; ++i) {                                         \
                int r = wm + i * 16 + col;                                        \
                a[i] = *(const bf16x8*)&Ah[r * 32 + (quad ^ ((r >> 1) & 3)) * 8]; \
                int c = wn + i * 16 + col;                                        \
                b[i] = *(const bf16x8*)&Bh[c * 32 + (quad ^ ((c >> 1) & 3)) * 8]; \
            }                                                                     \
            _Pragma("unroll")                                                     \
            for (int i = 0; i < 4; ++i)                                           \
                _Pragma("unroll")                                                 \
                for (int j = 0; j < 4; ++j)                                       \
                    acc[i][j] = __builtin_amdgcn_mfma_f32_16x16x32_bf16(          \
                        a[i], b[j], acc[i][j], 0, 0, 0);                          \
        }                                                                         \
        __syncthreads();                                                          \
    }

// ---------------- QK GEMM: X[8192,1024] @ Wqk[2048,1024]^T + bias -> Q,K ----------------
__global__ __launch_bounds__(256) void gemm_qk(
    const ushort* __restrict__ A,
    const ushort* __restrict__ W,
    const float*  __restrict__ bias,
    ushort* __restrict__ Qb, ushort* __restrict__ Kb)
{
    __shared__ ushort As0[128 * 32];
    __shared__ ushort As1[128 * 32];
    __shared__ ushort Bs0[128 * 32];
    __shared__ ushort Bs1[128 * 32];
    const int tid  = threadIdx.x;
    const int lane = tid & 63;
    const int wave = tid >> 6;
    const int col  = lane & 15;
    const int quad = lane >> 4;
    const int m0 = blockIdx.x * 128;
    const int n0 = blockIdx.y * 128;
    const int wm = (wave >> 1) * 64;
    const int wn = (wave & 1) * 64;

    GEMM_BODY64(A, W, m0, n0)

    #pragma unroll
    for (int i = 0; i < 4; ++i)
        #pragma unroll
        for (int j = 0; j < 4; ++j)
            #pragma unroll
            for (int r = 0; r < 4; ++r) {
                int m = m0 + wm + i * 16 + quad * 4 + r;
                int n = n0 + wn + j * 16 + col;
                float v = acc[i][j][r] + bias[n];
                unsigned short bv = f2bf(v);
                int e = n & 1023;
                int h = e >> 6, d = e & 63;
                int b = m >> 11, s = m & 2047;
                size_t bh = (size_t)(b * NHEAD + h);
                if (n < 1024) Qb[(bh * SEQ + s) * HDIM + d] = bv;
                else          Kb[(bh * SEQ + s) * HDIM + d] = bv;
            }
}

// ---------------- V^T GEMM: Wv[1024,1024] @ X^T -> Vtx[1024,8192] + bias(m) ----------------
__global__ __launch_bounds__(256) void gemm_vt(
    const ushort* __restrict__ Wv,
    const ushort* __restrict__ X,
    const float*  __restrict__ bias,
    ushort* __restrict__ Vtx)
{
    __shared__ ushort As0[128 * 32];
    __shared__ ushort As1[128 * 32];
    __shared__ ushort Bs0[128 * 32];
    __shared__ ushort Bs1[128 * 32];
    const int tid  = threadIdx.x;
    const int lane = tid & 63;
    const int wave = tid >> 6;
    const int col  = lane & 15;
    const int quad = lane >> 4;
    const int m0 = blockIdx.x * 128;   // channel
    const int n0 = blockIdx.y * 128;   // token
    const int wm = (wave >> 1) * 64;
    const int wn = (wave & 1) * 64;

    GEMM_BODY64(Wv, X, m0, n0)

    #pragma unroll
    for (int i = 0; i < 4; ++i)
        #pragma unroll
        for (int j = 0; j < 4; ++j)
            #pragma unroll
            for (int r = 0; r < 4; ++r) {
                int m = m0 + wm + i * 16 + quad * 4 + r;
                int n = n0 + wn + j * 16 + col;
                Vtx[(size_t)m * NTOK + n] = f2bf(acc[i][j][r] + bias[m]);
            }
}

// ---------------- Output proj + bias -> fp32 out ----------------
__global__ __launch_bounds__(256) void gemm_proj(
    const ushort* __restrict__ A,
    const ushort* __restrict__ W,
    const float*  __restrict__ bias,
    float* __restrict__ out)
{
    __shared__ ushort As0[128 * 32];
    __shared__ ushort As1[128 * 32];
    __shared__ ushort Bs0[128 * 32];
    __shared__ ushort Bs1[128 * 32];
    const int tid  = threadIdx.x;
    const int lane = tid & 63;
    const int wave = tid >> 6;
    const int col  = lane & 15;
    const int quad = lane >> 4;
    const int m0 = blockIdx.x * 128;
    const int n0 = blockIdx.y * 128;
    const int wm = (wave >> 1) * 64;
    const int wn = (wave & 1) * 64;

    GEMM_BODY64(A, W, m0, n0)

    #pragma unroll
    for (int i = 0; i < 4; ++i)
        #pragma unroll
        for (int j = 0; j < 4; ++j)
            #pragma unroll
            for (int r = 0; r < 4; ++r) {
                int m = m0 + wm + i * 16 + quad * 4 + r;
                int n = n0 + wn + j * 16 + col;
                out[(size_t)m * EMB + n] = acc[i][j][r] + bias[n];
            }
}

// ---------------- Flash attention: LDS-staged K/V, 32 q-rows per wave ----------------
// r6: VALU diet — raw v_exp_f32 via __builtin_amdgcn_exp2f (scores bounded, no
// range guard needed), pack via compiler cvt_pk, causal mask hoisted to a
// separate last-tile path. P-scratch reused serially per q-group (4KB/wave) ->
// LDS 48KB -> 3 blocks/CU. Structure otherwise = r5 (2 q-groups amortize K/V frags).
__device__ __forceinline__ void attn_qtile(
    int qt, int b, int h, int lane, int wave,
    const ushort* __restrict__ Qh, const ushort* __restrict__ Kh,
    const ushort* __restrict__ Vh, ushort* __restrict__ Yb,
    ushort* __restrict__ Ks0, ushort* __restrict__ Ks1, ushort* __restrict__ Vs,
    ushort* __restrict__ Ps)
{
    const int col  = lane & 15;
    const int quad = lane >> 4;
    const int q0   = qt * 128 + wave * 32;
    const float SC = 0.125f * 1.44269504f;

    bf16x8 qf[2][2];
    #pragma unroll
    for (int g = 0; g < 2; ++g) {
        const ushort* qp = Qh + (size_t)(q0 + g * 16 + col) * HDIM;
        qf[g][0] = *(const bf16x8*)(qp + quad * 8);
        qf[g][1] = *(const bf16x8*)(qp + 32 + quad * 8);
    }

    // per-wave private 4KB transpose scratch, reused serially by both q-groups
    ushort* Pw = Ps + wave * 2048;

    f32x4 o[2][4] = {};
    float lrun[2] = {0.f, 0.f};

    const int nk = qt + 1;
    for (int kt = 0; kt < nk; ++kt) {
        const int k0 = kt * 128;
        const bool last = (kt == nk - 1);

        // ---- stage: K halves (2 rounds each) + V quarters (8 glds/thread) ----
        {
            int srow = wave * 16 + (lane >> 2);
            #pragma unroll
            for (int rr = 0; rr < 2; ++rr) {
                int r = rr * 64 + srow;
                int kc = (lane & 3) ^ ((r >> 1) & 3);
                const ushort* src = Kh + (size_t)(k0 + r) * HDIM + kc * 8;
                async_copy16(src,      Ks0 + (rr * 64 + wave * 16) * 32);
                async_copy16(src + 32, Ks1 + (rr * 64 + wave * 16) * 32);
            }
            int kc = (lane & 3) ^ ((srow >> 1) & 3);
            const ushort* vsrc = Vh + (size_t)srow * NTOK + k0 + kc * 8;
            #pragma unroll
            for (int kq = 0; kq < 4; ++kq)
                async_copy16(vsrc + kq * 32, Vs + kq * 2048 + (wave * 16) * 32);
        }
        __syncthreads();

        // ---- S^T = K @ Q^T : 8 j-tiles of 16 keys, K frags shared by 2 q-groups ----
        f32x4 st[2][8];
        #pragma unroll
        for (int j = 0; j < 8; ++j) {
            int r = j * 16 + col;
            int q_ = (quad ^ ((r >> 1) & 3)) * 8;
            bf16x8 kf0 = *(const bf16x8*)&Ks0[r * 32 + q_];
            bf16x8 kf1 = *(const bf16x8*)&Ks1[r * 32 + q_];
            #pragma unroll
            for (int g = 0; g < 2; ++g) {
                f32x4 z = {0.f, 0.f, 0.f, 0.f};
                f32x4 t = __builtin_amdgcn_mfma_f32_16x16x32_bf16(kf0, qf[g][0], z, 0, 0, 0);
                st[g][j] = __builtin_amdgcn_mfma_f32_16x16x32_bf16(kf1, qf[g][1], t, 0, 0, 0);
            }
        }

        // ---- p = exp2(s*SC) [raw v_exp_f32], mask only on last tile ----
        if (last) {
            #pragma unroll
            for (int g = 0; g < 2; ++g) {
                int rowg = q0 + g * 16 + col;
                #pragma unroll
                for (int j = 0; j < 8; ++j)
                    #pragma unroll
                    for (int r = 0; r < 4; ++r) {
                        float pv = __builtin_amdgcn_exp2f(st[g][j][r] * SC);
                        int c = k0 + j * 16 + quad * 4 + r;
                        pv = (c <= rowg) ? pv : 0.f;
                        st[g][j][r] = pv;
                        lrun[g] += pv;
                    }
            }
        } else {
            #pragma unroll
            for (int g = 0; g < 2; ++g)
                #pragma unroll
                for (int j = 0; j < 8; ++j)
                    #pragma unroll
                    for (int r = 0; r < 4; ++r) {
                        float pv = __builtin_amdgcn_exp2f(st[g][j][r] * SC);
                        st[g][j][r] = pv;
                        lrun[g] += pv;
                    }
        }

        // ---- P transpose via per-wave LDS scratch, serial per group (in-order DS) ----
        bf16x8 pf[2][4];
        #pragma unroll
        for (int g = 0; g < 2; ++g) {
            #pragma unroll
            for (int j = 0; j < 8; ++j) {
                int blk = 2 * j + (quad >> 1);
                *(unsigned long long*)&Pw[col * 128 + ((blk ^ col) & 15) * 8 + (quad & 1) * 4]
                    = pack_bf4(st[g][j]);
            }
            #pragma unroll
            for (int kq = 0; kq < 4; ++kq) {
                int blk = 4 * kq + quad;
                pf[g][kq] = *(const bf16x8*)&Pw[col * 128 + ((blk ^ col) & 15) * 8];
            }
        }

        // ---- O^T += V^T @ P^T : V frags shared by 2 q-groups ----
        #pragma unroll
        for (int dt = 0; dt < 4; ++dt) {
            int r = dt * 16 + col;
            int q_ = (quad ^ ((r >> 1) & 3)) * 8;
            #pragma unroll
            for (int kq = 0; kq < 4; ++kq) {
                bf16x8 vf = *(const bf16x8*)&Vs[kq * 2048 + r * 32 + q_];
                o[0][dt] = __builtin_amdgcn_mfma_f32_16x16x32_bf16(vf, pf[0][kq], o[0][dt], 0, 0, 0);
                o[1][dt] = __builtin_amdgcn_mfma_f32_16x16x32_bf16(vf, pf[1][kq], o[1][dt], 0, 0, 0);
            }
        }
        __syncthreads();
    }

    // ---- epilogue per q-group ----
    #pragma unroll
    for (int g = 0; g < 2; ++g) {
        float l = lrun[g];
        l += __shfl_xor(l, 16, 64);
        l += __shfl_xor(l, 32, 64);
        float inv = 1.f / l;
        int rowg = q0 + g * 16 + col;
        size_t rbase = ((size_t)(b * SEQ + rowg)) * EMB + h * HDIM + quad * 4;
        #pragma unroll
        for (int dt = 0; dt < 4; ++dt) {
            ushort4 s4;
            s4.x = f2bf(o[g][dt][0] * inv);
            s4.y = f2bf(o[g][dt][1] * inv);
            s4.z = f2bf(o[g][dt][2] * inv);
            s4.w = f2bf(o[g][dt][3] * inv);
            *(ushort4*)(Yb + rbase + dt * 16) = s4;
        }
    }
}

__global__ __launch_bounds__(256, 3) void attn(
    const ushort* __restrict__ Qb, const ushort* __restrict__ Kb,
    const ushort* __restrict__ Vtx, ushort* __restrict__ Yb)
{
    __shared__ ushort Ks0[128 * 32];   // K d=0..31
    __shared__ ushort Ks1[128 * 32];   // K d=32..63
    __shared__ ushort Vs[4 * 64 * 32]; // V^T key-quarters
    __shared__ __align__(16) ushort Ps[4 * 2048]; // per-wave P-transpose scratch (4KB ea)
    const int lane = threadIdx.x & 63;
    const int wave = threadIdx.x >> 6;
    const int bh   = blockIdx.x & 63;   // b*16+h ; same-bh blocks share an XCD
    const int pr   = blockIdx.x >> 6;   // q-tile pair {15-pr, pr}: 17 k-tiles/block

    const int b = bh >> 4, h = bh & 15;
    const ushort* Qh = Qb + (size_t)bh * SEQ * HDIM;
    const ushort* Kh = Kb + (size_t)bh * SEQ * HDIM;
    const ushort* Vh = Vtx + (size_t)(h * HDIM) * NTOK + b * SEQ;

    attn_qtile(15 - pr, b, h, lane, wave, Qh, Kh, Vh, Yb, Ks0, Ks1, Vs, Ps);
    __syncthreads();
    attn_qtile(pr,      b, h, lane, wave, Qh, Kh, Vh, Yb, Ks0, Ks1, Vs, Ps);
}

extern "C" void kernel_launch(void* const* d_in, const int* in_sizes, int n_in,
                              void* d_out, int out_size, void* d_ws, size_t ws_size,
                              hipStream_t stream) {
    const float* x      = (const float*)d_in[0];
    const float* W_qkv  = (const float*)d_in[1];
    const float* b_qkv  = (const float*)d_in[2];
    const float* W_proj = (const float*)d_in[3];
    const float* b_proj = (const float*)d_in[4];
    float* out = (float*)d_out;

    ushort* ws     = (ushort*)d_ws;
    ushort* Xb     = ws;                 // reused as Yb after attn inputs ready
    ushort* Yb     = ws;
    ushort* Wqkvb  = ws + 8388608;
    ushort* Wprojb = ws + 11534336;
    ushort* Qb     = ws + 12582912;
    ushort* Kb     = ws + 20971520;
    ushort* Vtx    = ws + 29360128;      // [1024 channels][8192 tokens]

    cvt_f32_bf16<<<8192, 256, 0, stream>>>((const float4*)x,      Xb,     2097152);
    cvt_f32_bf16<<<3072, 256, 0, stream>>>((const float4*)W_qkv,  Wqkvb,  786432);
    cvt_f32_bf16<<<1024, 256, 0, stream>>>((const float4*)W_proj, Wprojb, 262144);

    gemm_qk<<<dim3(64, 16), 256, 0, stream>>>(Xb, Wqkvb, b_qkv, Qb, Kb);
    gemm_vt<<<dim3(8, 64), 256, 0, stream>>>(Wqkvb + (size_t)2048 * EMB, Xb,
                                             b_qkv + 2048, Vtx);
    attn<<<512, 256, 0, stream>>>(Qb, Kb, Vtx, Yb);
    gemm_proj<<<dim3(64, 8), 256, 0, stream>>>(Yb, Wprojb, b_proj, out);
}

// Round 8
// 245.810 us; speedup vs baseline: 1.4155x; 1.4155x over previous
//
#include <hip/hip_runtime.h>
#include <hip/hip_bf16.h>

typedef __attribute__((ext_vector_type(4))) float f32x4;
typedef __attribute__((ext_vector_type(8))) __bf16 bf16x8;
typedef __attribute__((ext_vector_type(4))) unsigned int u32x4;

#define EMB 1024
#define NHEAD 16
#define HDIM 64
#define SEQ 2048
#define BATCH 4
#define NTOK 8192

__device__ __forceinline__ unsigned short f2bf(float f) {
    unsigned int u = __builtin_bit_cast(unsigned int, f);
    u = (u + 0x7fffu + ((u >> 16) & 1u)) >> 16;
    return (unsigned short)u;
}

// packed 2x f32->bf16 ; compiler lowers the cast pair to v_cvt_pk_bf16_f32
__device__ __forceinline__ unsigned int cvt2_bf16(float lo, float hi) {
    unsigned short a = __builtin_bit_cast(unsigned short, (__bf16)lo);
    unsigned short b = __builtin_bit_cast(unsigned short, (__bf16)hi);
    return (unsigned int)a | ((unsigned int)b << 16);
}

__device__ __forceinline__ unsigned long long pack_bf4(const f32x4 v) {
    unsigned long long lo = cvt2_bf16(v[0], v[1]);
    unsigned long long hi = cvt2_bf16(v[2], v[3]);
    return lo | (hi << 32);
}

__device__ __forceinline__ void async_copy16(const ushort* g, ushort* l) {
    __builtin_amdgcn_global_load_lds(
        (const __attribute__((address_space(1))) void*)g,
        (__attribute__((address_space(3))) void*)l,
        16, 0, 0);
}

// ---------------- fp32 -> bf16 convert ----------------
__global__ void cvt_f32_bf16(const float4* __restrict__ in, ushort* __restrict__ out, int n4) {
    int i = blockIdx.x * 256 + threadIdx.x;
    if (i < n4) {
        float4 v = in[i];
        ushort4 o;
        o.x = f2bf(v.x); o.y = f2bf(v.y); o.z = f2bf(v.z); o.w = f2bf(v.w);
        ((ushort4*)out)[i] = o;
    }
}

// ================= 128x128-tile GEMM core, BK=64 (r6: halved barrier count) ======
#define GEMM_STAGE64(Asrc, Bsrc, m0, n0, kt)                                      \
    {                                                                             \
        _Pragma("unroll")                                                         \
        for (int j = 0; j < 2; ++j) {                                             \
            int row = wave * 32 + j * 16 + (lane >> 2);                           \
            int kc  = (lane & 3) ^ ((row >> 1) & 3);                              \
            const ushort* asrc = Asrc + (size_t)(m0 + row) * EMB + kt + kc * 8;   \
            const ushort* bsrc = Bsrc + (size_t)(n0 + row) * EMB + kt + kc * 8;   \
            async_copy16(asrc,      As0 + (wave * 32 + j * 16) * 32);             \
            async_copy16(asrc + 32, As1 + (wave * 32 + j * 16) * 32);             \
            async_copy16(bsrc,      Bs0 + (wave * 32 + j * 16) * 32);             \
            async_copy16(bsrc + 32, Bs1 + (wave * 32 + j * 16) * 32);             \
        }                                                                         \
    }

#define GEMM_BODY64(Asrc, Bsrc, m0, n0)                                           \
    f32x4 acc[4][4] = {};                                                         \
    for (int kt = 0; kt < EMB; kt += 64) {                                        \
        GEMM_STAGE64(Asrc, Bsrc, m0, n0, kt)                                      \
        __syncthreads();                                                          \
        _Pragma("unroll")                                                         \
        for (int hf = 0; hf < 2; ++hf) {                                          \
            const ushort* Ah = hf ? As1 : As0;                                    \
            const ushort* Bh = hf ? Bs1 : Bs0;                                    \
            bf16x8 a[4], b[4];                                                    \
            _Pragma("unroll")                                                     \
            for (int i = 0; i < 4; ++i) {                                         \
                int r = wm + i * 16 + col;                                        \
                a[i] = *(const bf16x8*)&Ah[r * 32 + (quad ^ ((r >> 1) & 3)) * 8]; \
                int c = wn + i * 16 + col;                                        \
                b[i] = *(const bf16x8*)&Bh[c * 32 + (quad ^ ((c >> 1) & 3)) * 8]; \
            }                                                                     \
            _Pragma("unroll")                                                     \
            for (int i = 0; i < 4; ++i)                                           \
                _Pragma("unroll")                                                 \
                for (int j = 0; j < 4; ++j)                                       \
                    acc[i][j] = __builtin_amdgcn_mfma_f32_16x16x32_bf16(          \
                        a[i], b[j], acc[i][j], 0, 0, 0);                          \
        }                                                                         \
        __syncthreads();                                                          \
    }

// ---------------- QK GEMM: X[8192,1024] @ Wqk[2048,1024]^T + bias -> Q,K ----------------
__global__ __launch_bounds__(256) void gemm_qk(
    const ushort* __restrict__ A,
    const ushort* __restrict__ W,
    const float*  __restrict__ bias,
    ushort* __restrict__ Qb, ushort* __restrict__ Kb)
{
    __shared__ ushort As0[128 * 32];
    __shared__ ushort As1[128 * 32];
    __shared__ ushort Bs0[128 * 32];
    __shared__ ushort Bs1[128 * 32];
    const int tid  = threadIdx.x;
    const int lane = tid & 63;
    const int wave = tid >> 6;
    const int col  = lane & 15;
    const int quad = lane >> 4;
    const int m0 = blockIdx.x * 128;
    const int n0 = blockIdx.y * 128;
    const int wm = (wave >> 1) * 64;
    const int wn = (wave & 1) * 64;

    GEMM_BODY64(A, W, m0, n0)

    #pragma unroll
    for (int i = 0; i < 4; ++i)
        #pragma unroll
        for (int j = 0; j < 4; ++j)
            #pragma unroll
            for (int r = 0; r < 4; ++r) {
                int m = m0 + wm + i * 16 + quad * 4 + r;
                int n = n0 + wn + j * 16 + col;
                float v = acc[i][j][r] + bias[n];
                unsigned short bv = f2bf(v);
                int e = n & 1023;
                int h = e >> 6, d = e & 63;
                int b = m >> 11, s = m & 2047;
                size_t bh = (size_t)(b * NHEAD + h);
                if (n < 1024) Qb[(bh * SEQ + s) * HDIM + d] = bv;
                else          Kb[(bh * SEQ + s) * HDIM + d] = bv;
            }
}

// ---------------- V^T GEMM: Wv[1024,1024] @ X^T -> Vtx[1024,8192] + bias(m) ----------------
__global__ __launch_bounds__(256) void gemm_vt(
    const ushort* __restrict__ Wv,
    const ushort* __restrict__ X,
    const float*  __restrict__ bias,
    ushort* __restrict__ Vtx)
{
    __shared__ ushort As0[128 * 32];
    __shared__ ushort As1[128 * 32];
    __shared__ ushort Bs0[128 * 32];
    __shared__ ushort Bs1[128 * 32];
    const int tid  = threadIdx.x;
    const int lane = tid & 63;
    const int wave = tid >> 6;
    const int col  = lane & 15;
    const int quad = lane >> 4;
    const int m0 = blockIdx.x * 128;   // channel
    const int n0 = blockIdx.y * 128;   // token
    const int wm = (wave >> 1) * 64;
    const int wn = (wave & 1) * 64;

    GEMM_BODY64(Wv, X, m0, n0)

    #pragma unroll
    for (int i = 0; i < 4; ++i)
        #pragma unroll
        for (int j = 0; j < 4; ++j)
            #pragma unroll
            for (int r = 0; r < 4; ++r) {
                int m = m0 + wm + i * 16 + quad * 4 + r;
                int n = n0 + wn + j * 16 + col;
                Vtx[(size_t)m * NTOK + n] = f2bf(acc[i][j][r] + bias[m]);
            }
}

// ---------------- Output proj + bias -> fp32 out ----------------
__global__ __launch_bounds__(256) void gemm_proj(
    const ushort* __restrict__ A,
    const ushort* __restrict__ W,
    const float*  __restrict__ bias,
    float* __restrict__ out)
{
    __shared__ ushort As0[128 * 32];
    __shared__ ushort As1[128 * 32];
    __shared__ ushort Bs0[128 * 32];
    __shared__ ushort Bs1[128 * 32];
    const int tid  = threadIdx.x;
    const int lane = tid & 63;
    const int wave = tid >> 6;
    const int col  = lane & 15;
    const int quad = lane >> 4;
    const int m0 = blockIdx.x * 128;
    const int n0 = blockIdx.y * 128;
    const int wm = (wave >> 1) * 64;
    const int wn = (wave & 1) * 64;

    GEMM_BODY64(A, W, m0, n0)

    #pragma unroll
    for (int i = 0; i < 4; ++i)
        #pragma unroll
        for (int j = 0; j < 4; ++j)
            #pragma unroll
            for (int r = 0; r < 4; ++r) {
                int m = m0 + wm + i * 16 + quad * 4 + r;
                int n = n0 + wn + j * 16 + col;
                out[(size_t)m * EMB + n] = acc[i][j][r] + bias[n];
            }
}

// ---------------- Flash attention: LDS-staged K/V, 32 q-rows per wave ----------------
// r7 post-mortem: __launch_bounds__(256,3) capped VGPRs at ~170 < live state ->
// scratch spill (WRITE_SIZE 16->273MB). Revert to (256,2); keep r6's VALU diet
// (raw v_exp_f32, cvt_pk pack, hoisted causal mask) and 4KB serial P-scratch.
// Structure = r5: 2 q-groups/wave amortize staged K/V frags; 2 barriers/tile.
__device__ __forceinline__ void attn_qtile(
    int qt, int b, int h, int lane, int wave,
    const ushort* __restrict__ Qh, const ushort* __restrict__ Kh,
    const ushort* __restrict__ Vh, ushort* __restrict__ Yb,
    ushort* __restrict__ Ks0, ushort* __restrict__ Ks1, ushort* __restrict__ Vs,
    ushort* __restrict__ Ps)
{
    const int col  = lane & 15;
    const int quad = lane >> 4;
    const int q0   = qt * 128 + wave * 32;
    const float SC = 0.125f * 1.44269504f;

    bf16x8 qf[2][2];
    #pragma unroll
    for (int g = 0; g < 2; ++g) {
        const ushort* qp = Qh + (size_t)(q0 + g * 16 + col) * HDIM;
        qf[g][0] = *(const bf16x8*)(qp + quad * 8);
        qf[g][1] = *(const bf16x8*)(qp + 32 + quad * 8);
    }

    // per-wave private 4KB transpose scratch, reused serially by both q-groups
    ushort* Pw = Ps + wave * 2048;

    f32x4 o[2][4] = {};
    float lrun[2] = {0.f, 0.f};

    const int nk = qt + 1;
    for (int kt = 0; kt < nk; ++kt) {
        const int k0 = kt * 128;
        const bool last = (kt == nk - 1);

        // ---- stage: K halves (2 rounds each) + V quarters (8 glds/thread) ----
        {
            int srow = wave * 16 + (lane >> 2);
            #pragma unroll
            for (int rr = 0; rr < 2; ++rr) {
                int r = rr * 64 + srow;
                int kc = (lane & 3) ^ ((r >> 1) & 3);
                const ushort* src = Kh + (size_t)(k0 + r) * HDIM + kc * 8;
                async_copy16(src,      Ks0 + (rr * 64 + wave * 16) * 32);
                async_copy16(src + 32, Ks1 + (rr * 64 + wave * 16) * 32);
            }
            int kc = (lane & 3) ^ ((srow >> 1) & 3);
            const ushort* vsrc = Vh + (size_t)srow * NTOK + k0 + kc * 8;
            #pragma unroll
            for (int kq = 0; kq < 4; ++kq)
                async_copy16(vsrc + kq * 32, Vs + kq * 2048 + (wave * 16) * 32);
        }
        __syncthreads();

        // ---- S^T = K @ Q^T : 8 j-tiles of 16 keys, K frags shared by 2 q-groups ----
        f32x4 st[2][8];
        #pragma unroll
        for (int j = 0; j < 8; ++j) {
            int r = j * 16 + col;
            int q_ = (quad ^ ((r >> 1) & 3)) * 8;
            bf16x8 kf0 = *(const bf16x8*)&Ks0[r * 32 + q_];
            bf16x8 kf1 = *(const bf16x8*)&Ks1[r * 32 + q_];
            #pragma unroll
            for (int g = 0; g < 2; ++g) {
                f32x4 z = {0.f, 0.f, 0.f, 0.f};
                f32x4 t = __builtin_amdgcn_mfma_f32_16x16x32_bf16(kf0, qf[g][0], z, 0, 0, 0);
                st[g][j] = __builtin_amdgcn_mfma_f32_16x16x32_bf16(kf1, qf[g][1], t, 0, 0, 0);
            }
        }

        // ---- p = exp2(s*SC) [raw v_exp_f32], mask only on last tile ----
        if (last) {
            #pragma unroll
            for (int g = 0; g < 2; ++g) {
                int rowg = q0 + g * 16 + col;
                #pragma unroll
                for (int j = 0; j < 8; ++j)
                    #pragma unroll
                    for (int r = 0; r < 4; ++r) {
                        float pv = __builtin_amdgcn_exp2f(st[g][j][r] * SC);
                        int c = k0 + j * 16 + quad * 4 + r;
                        pv = (c <= rowg) ? pv : 0.f;
                        st[g][j][r] = pv;
                        lrun[g] += pv;
                    }
            }
        } else {
            #pragma unroll
            for (int g = 0; g < 2; ++g)
                #pragma unroll
                for (int j = 0; j < 8; ++j)
                    #pragma unroll
                    for (int r = 0; r < 4; ++r) {
                        float pv = __builtin_amdgcn_exp2f(st[g][j][r] * SC);
                        st[g][j][r] = pv;
                        lrun[g] += pv;
                    }
        }

        // ---- P transpose via per-wave LDS scratch, serial per group (in-order DS) ----
        bf16x8 pf[2][4];
        #pragma unroll
        for (int g = 0; g < 2; ++g) {
            #pragma unroll
            for (int j = 0; j < 8; ++j) {
                int blk = 2 * j + (quad >> 1);
                *(unsigned long long*)&Pw[col * 128 + ((blk ^ col) & 15) * 8 + (quad & 1) * 4]
                    = pack_bf4(st[g][j]);
            }
            #pragma unroll
            for (int kq = 0; kq < 4; ++kq) {
                int blk = 4 * kq + quad;
                pf[g][kq] = *(const bf16x8*)&Pw[col * 128 + ((blk ^ col) & 15) * 8];
            }
        }

        // ---- O^T += V^T @ P^T : V frags shared by 2 q-groups ----
        #pragma unroll
        for (int dt = 0; dt < 4; ++dt) {
            int r = dt * 16 + col;
            int q_ = (quad ^ ((r >> 1) & 3)) * 8;
            #pragma unroll
            for (int kq = 0; kq < 4; ++kq) {
                bf16x8 vf = *(const bf16x8*)&Vs[kq * 2048 + r * 32 + q_];
                o[0][dt] = __builtin_amdgcn_mfma_f32_16x16x32_bf16(vf, pf[0][kq], o[0][dt], 0, 0, 0);
                o[1][dt] = __builtin_amdgcn_mfma_f32_16x16x32_bf16(vf, pf[1][kq], o[1][dt], 0, 0, 0);
            }
        }
        __syncthreads();
    }

    // ---- epilogue per q-group ----
    #pragma unroll
    for (int g = 0; g < 2; ++g) {
        float l = lrun[g];
        l += __shfl_xor(l, 16, 64);
        l += __shfl_xor(l, 32, 64);
        float inv = 1.f / l;
        int rowg = q0 + g * 16 + col;
        size_t rbase = ((size_t)(b * SEQ + rowg)) * EMB + h * HDIM + quad * 4;
        #pragma unroll
        for (int dt = 0; dt < 4; ++dt) {
            ushort4 s4;
            s4.x = f2bf(o[g][dt][0] * inv);
            s4.y = f2bf(o[g][dt][1] * inv);
            s4.z = f2bf(o[g][dt][2] * inv);
            s4.w = f2bf(o[g][dt][3] * inv);
            *(ushort4*)(Yb + rbase + dt * 16) = s4;
        }
    }
}

__global__ __launch_bounds__(256, 2) void attn(
    const ushort* __restrict__ Qb, const ushort* __restrict__ Kb,
    const ushort* __restrict__ Vtx, ushort* __restrict__ Yb)
{
    __shared__ ushort Ks0[128 * 32];   // K d=0..31
    __shared__ ushort Ks1[128 * 32];   // K d=32..63
    __shared__ ushort Vs[4 * 64 * 32]; // V^T key-quarters
    __shared__ __align__(16) ushort Ps[4 * 2048]; // per-wave P-transpose scratch (4KB ea)
    const int lane = threadIdx.x & 63;
    const int wave = threadIdx.x >> 6;
    const int bh   = blockIdx.x & 63;   // b*16+h ; same-bh blocks share an XCD
    const int pr   = blockIdx.x >> 6;   // q-tile pair {15-pr, pr}: 17 k-tiles/block

    const int b = bh >> 4, h = bh & 15;
    const ushort* Qh = Qb + (size_t)bh * SEQ * HDIM;
    const ushort* Kh = Kb + (size_t)bh * SEQ * HDIM;
    const ushort* Vh = Vtx + (size_t)(h * HDIM) * NTOK + b * SEQ;

    attn_qtile(15 - pr, b, h, lane, wave, Qh, Kh, Vh, Yb, Ks0, Ks1, Vs, Ps);
    __syncthreads();
    attn_qtile(pr,      b, h, lane, wave, Qh, Kh, Vh, Yb, Ks0, Ks1, Vs, Ps);
}

extern "C" void kernel_launch(void* const* d_in, const int* in_sizes, int n_in,
                              void* d_out, int out_size, void* d_ws, size_t ws_size,
                              hipStream_t stream) {
    const float* x      = (const float*)d_in[0];
    const float* W_qkv  = (const float*)d_in[1];
    const float* b_qkv  = (const float*)d_in[2];
    const float* W_proj = (const float*)d_in[3];
    const float* b_proj = (const float*)d_in[4];
    float* out = (float*)d_out;

    ushort* ws     = (ushort*)d_ws;
    ushort* Xb     = ws;                 // reused as Yb after attn inputs ready
    ushort* Yb     = ws;
    ushort* Wqkvb  = ws + 8388608;
    ushort* Wprojb = ws + 11534336;
    ushort* Qb     = ws + 12582912;
    ushort* Kb     = ws + 20971520;
    ushort* Vtx    = ws + 29360128;      // [1024 channels][8192 tokens]

    cvt_f32_bf16<<<8192, 256, 0, stream>>>((const float4*)x,      Xb,     2097152);
    cvt_f32_bf16<<<3072, 256, 0, stream>>>((const float4*)W_qkv,  Wqkvb,  786432);
    cvt_f32_bf16<<<1024, 256, 0, stream>>>((const float4*)W_proj, Wprojb, 262144);

    gemm_qk<<<dim3(64, 16), 256, 0, stream>>>(Xb, Wqkvb, b_qkv, Qb, Kb);
    gemm_vt<<<dim3(8, 64), 256, 0, stream>>>(Wqkvb + (size_t)2048 * EMB, Xb,
                                             b_qkv + 2048, Vtx);
    attn<<<512, 256, 0, stream>>>(Qb, Kb, Vtx, Yb);
    gemm_proj<<<dim3(64, 8), 256, 0, stream>>>(Yb, Wprojb, b_proj, out);
}

// Round 10
// 244.679 us; speedup vs baseline: 1.4221x; 1.0046x over previous
//
#include <hip/hip_runtime.h>
#include <hip/hip_bf16.h>

typedef __attribute__((ext_vector_type(4))) float f32x4;
typedef __attribute__((ext_vector_type(16))) float f32x16;
typedef __attribute__((ext_vector_type(8))) __bf16 bf16x8;
typedef __attribute__((ext_vector_type(4))) unsigned int u32x4;

#define EMB 1024
#define NHEAD 16
#define HDIM 64
#define SEQ 2048
#define BATCH 4
#define NTOK 8192

__device__ __forceinline__ unsigned short f2bf(float f) {
    unsigned int u = __builtin_bit_cast(unsigned int, f);
    u = (u + 0x7fffu + ((u >> 16) & 1u)) >> 16;
    return (unsigned short)u;
}

// packed 2x f32->bf16 ; compiler lowers the cast pair to v_cvt_pk_bf16_f32
__device__ __forceinline__ unsigned int cvt2_bf16(float lo, float hi) {
    unsigned short a = __builtin_bit_cast(unsigned short, (__bf16)lo);
    unsigned short b = __builtin_bit_cast(unsigned short, (__bf16)hi);
    return (unsigned int)a | ((unsigned int)b << 16);
}

// v_permlane32_swap_b32 vdst, vsrc — swaps vdst's HIGH half with vsrc's LOW half:
//   vdst'[l] = (l<32) ? vdst[l] : vsrc[l-32]
//   vsrc'[l] = (l<32) ? vdst[l+32] : vsrc[l]
// (direction verified against the m214 recipe: one swap yields two usable words)
__device__ __forceinline__ void permlane32_swap(unsigned int &x, unsigned int &y) {
    asm volatile("v_permlane32_swap_b32 %0, %1" : "+v"(x), "+v"(y));
}

__device__ __forceinline__ void async_copy16(const ushort* g, ushort* l) {
    __builtin_amdgcn_global_load_lds(
        (const __attribute__((address_space(1))) void*)g,
        (__attribute__((address_space(3))) void*)l,
        16, 0, 0);
}

// ---------------- fp32 -> bf16 convert ----------------
__global__ void cvt_f32_bf16(const float4* __restrict__ in, ushort* __restrict__ out, int n4) {
    int i = blockIdx.x * 256 + threadIdx.x;
    if (i < n4) {
        float4 v = in[i];
        ushort4 o;
        o.x = f2bf(v.x); o.y = f2bf(v.y); o.z = f2bf(v.z); o.w = f2bf(v.w);
        ((ushort4*)out)[i] = o;
    }
}

// ================= 128x128-tile GEMM core, BK=64 (r6: halved barrier count) ======
#define GEMM_STAGE64(Asrc, Bsrc, m0, n0, kt)                                      \
    {                                                                             \
        _Pragma("unroll")                                                         \
        for (int j = 0; j < 2; ++j) {                                             \
            int row = wave * 32 + j * 16 + (lane >> 2);                           \
            int kc  = (lane & 3) ^ ((row >> 1) & 3);                              \
            const ushort* asrc = Asrc + (size_t)(m0 + row) * EMB + kt + kc * 8;   \
            const ushort* bsrc = Bsrc + (size_t)(n0 + row) * EMB + kt + kc * 8;   \
            async_copy16(asrc,      As0 + (wave * 32 + j * 16) * 32);             \
            async_copy16(asrc + 32, As1 + (wave * 32 + j * 16) * 32);             \
            async_copy16(bsrc,      Bs0 + (wave * 32 + j * 16) * 32);             \
            async_copy16(bsrc + 32, Bs1 + (wave * 32 + j * 16) * 32);             \
        }                                                                         \
    }

#define GEMM_BODY64(Asrc, Bsrc, m0, n0)                                           \
    f32x4 acc[4][4] = {};                                                         \
    for (int kt = 0; kt < EMB; kt += 64) {                                        \
        GEMM_STAGE64(Asrc, Bsrc, m0, n0, kt)                                      \
        __syncthreads();                                                          \
        _Pragma("unroll")                                                         \
        for (int hf = 0; hf < 2; ++hf) {                                          \
            const ushort* Ah = hf ? As1 : As0;                                    \
            const ushort* Bh = hf ? Bs1 : Bs0;                                    \
            bf16x8 a[4], b[4];                                                    \
            _Pragma("unroll")                                                     \
            for (int i = 0; i < 4; ++i) {                                         \
                int r = wm + i * 16 + col;                                        \
                a[i] = *(const bf16x8*)&Ah[r * 32 + (quad ^ ((r >> 1) & 3)) * 8]; \
                int c = wn + i * 16 + col;                                        \
                b[i] = *(const bf16x8*)&Bh[c * 32 + (quad ^ ((c >> 1) & 3)) * 8]; \
            }                                                                     \
            _Pragma("unroll")                                                     \
            for (int i = 0; i < 4; ++i)                                           \
                _Pragma("unroll")                                                 \
                for (int j = 0; j < 4; ++j)                                       \
                    acc[i][j] = __builtin_amdgcn_mfma_f32_16x16x32_bf16(          \
                        a[i], b[j], acc[i][j], 0, 0, 0);                          \
        }                                                                         \
        __syncthreads();                                                          \
    }

// ---------------- QK GEMM: X[8192,1024] @ Wqk[2048,1024]^T + bias -> Q,K ----------------
__global__ __launch_bounds__(256) void gemm_qk(
    const ushort* __restrict__ A,
    const ushort* __restrict__ W,
    const float*  __restrict__ bias,
    ushort* __restrict__ Qb, ushort* __restrict__ Kb)
{
    __shared__ ushort As0[128 * 32];
    __shared__ ushort As1[128 * 32];
    __shared__ ushort Bs0[128 * 32];
    __shared__ ushort Bs1[128 * 32];
    const int tid  = threadIdx.x;
    const int lane = tid & 63;
    const int wave = tid >> 6;
    const int col  = lane & 15;
    const int quad = lane >> 4;
    const int m0 = blockIdx.x * 128;
    const int n0 = blockIdx.y * 128;
    const int wm = (wave >> 1) * 64;
    const int wn = (wave & 1) * 64;

    GEMM_BODY64(A, W, m0, n0)

    #pragma unroll
    for (int i = 0; i < 4; ++i)
        #pragma unroll
        for (int j = 0; j < 4; ++j)
            #pragma unroll
            for (int r = 0; r < 4; ++r) {
                int m = m0 + wm + i * 16 + quad * 4 + r;
                int n = n0 + wn + j * 16 + col;
                float v = acc[i][j][r] + bias[n];
                unsigned short bv = f2bf(v);
                int e = n & 1023;
                int h = e >> 6, d = e & 63;
                int b = m >> 11, s = m & 2047;
                size_t bh = (size_t)(b * NHEAD + h);
                if (n < 1024) Qb[(bh * SEQ + s) * HDIM + d] = bv;
                else          Kb[(bh * SEQ + s) * HDIM + d] = bv;
            }
}

// ---------------- V^T GEMM: Wv[1024,1024] @ X^T -> Vtx[1024,8192] + bias(m) ----------------
__global__ __launch_bounds__(256) void gemm_vt(
    const ushort* __restrict__ Wv,
    const ushort* __restrict__ X,
    const float*  __restrict__ bias,
    ushort* __restrict__ Vtx)
{
    __shared__ ushort As0[128 * 32];
    __shared__ ushort As1[128 * 32];
    __shared__ ushort Bs0[128 * 32];
    __shared__ ushort Bs1[128 * 32];
    const int tid  = threadIdx.x;
    const int lane = tid & 63;
    const int wave = tid >> 6;
    const int col  = lane & 15;
    const int quad = lane >> 4;
    const int m0 = blockIdx.x * 128;   // channel
    const int n0 = blockIdx.y * 128;   // token
    const int wm = (wave >> 1) * 64;
    const int wn = (wave & 1) * 64;

    GEMM_BODY64(Wv, X, m0, n0)

    #pragma unroll
    for (int i = 0; i < 4; ++i)
        #pragma unroll
        for (int j = 0; j < 4; ++j)
            #pragma unroll
            for (int r = 0; r < 4; ++r) {
                int m = m0 + wm + i * 16 + quad * 4 + r;
                int n = n0 + wn + j * 16 + col;
                Vtx[(size_t)m * NTOK + n] = f2bf(acc[i][j][r] + bias[m]);
            }
}

// ---------------- Output proj + bias -> fp32 out ----------------
__global__ __launch_bounds__(256) void gemm_proj(
    const ushort* __restrict__ A,
    const ushort* __restrict__ W,
    const float*  __restrict__ bias,
    float* __restrict__ out)
{
    __shared__ ushort As0[128 * 32];
    __shared__ ushort As1[128 * 32];
    __shared__ ushort Bs0[128 * 32];
    __shared__ ushort Bs1[128 * 32];
    const int tid  = threadIdx.x;
    const int lane = tid & 63;
    const int wave = tid >> 6;
    const int col  = lane & 15;
    const int quad = lane >> 4;
    const int m0 = blockIdx.x * 128;
    const int n0 = blockIdx.y * 128;
    const int wm = (wave >> 1) * 64;
    const int wn = (wave & 1) * 64;

    GEMM_BODY64(A, W, m0, n0)

    #pragma unroll
    for (int i = 0; i < 4; ++i)
        #pragma unroll
        for (int j = 0; j < 4; ++j)
            #pragma unroll
            for (int r = 0; r < 4; ++r) {
                int m = m0 + wm + i * 16 + quad * 4 + r;
                int n = n0 + wn + j * 16 + col;
                out[(size_t)m * EMB + n] = acc[i][j][r] + bias[n];
            }
}

// ---------------- Flash attention: 32x32 MFMA + permlane P-exchange ----------------
// r9 failed on permlane routing direction; fixed here (see permlane32_swap doc).
// Wave owns 32 q-rows (ql=lane&31, hi=lane>>5). K/V staging & LDS layouts
// byte-identical to verified r8 code. Frag algebra:
//   QK A-frag: K[t*32+ql][c*16+hi*8..+7]  (Ks half c>>1, chunk position swz)
//   C layout (m74): row(key/d) = (reg&3)+8*(reg>>2)+4*hi, col = lane&31
//   P B-frag per 16 keys kc: Ap[m]=pk(keys 8m+4hi+{0,1}), Bp[m]=+{2,3};
//     swap(Ap[2kc],Ap[2kc+1]) -> w0,w2 ; swap(Bp[2kc],Bp[2kc+1]) -> w1,w3
//   PV A-frag: V^T[dt*32+ql][t*32+kc*16+hi*8..+7] (Vs quarter t)
// Fixed-max exp2 softmax (scores bounded); 2 blocks/CU, LDS 32KB (P-scratch freed).
__device__ __forceinline__ void attn_qtile(
    int qt, int b, int h, int lane, int wave,
    const ushort* __restrict__ Qh, const ushort* __restrict__ Kh,
    const ushort* __restrict__ Vh, ushort* __restrict__ Yb,
    ushort* __restrict__ Ks0, ushort* __restrict__ Ks1, ushort* __restrict__ Vs)
{
    const int ql = lane & 31;
    const int hi = lane >> 5;
    const int q0 = qt * 128 + wave * 32;
    const int qrow = q0 + ql;
    const float SC = 0.125f * 1.44269504f;

    // Q B-frags: qb[c] = Q[qrow][c*16 + hi*8 .. +7]
    bf16x8 qb[4];
    #pragma unroll
    for (int c = 0; c < 4; ++c)
        qb[c] = *(const bf16x8*)(Qh + (size_t)qrow * HDIM + c * 16 + hi * 8);

    f32x16 o2[2] = {};
    float lrun = 0.f;

    const int nk = qt + 1;
    for (int kt = 0; kt < nk; ++kt) {
        const int k0 = kt * 128;
        const bool last = (kt == nk - 1);

        // ---- stage: K halves (2 rounds each) + V quarters (8 glds/thread) ----
        {
            int srow = wave * 16 + (lane >> 2);
            #pragma unroll
            for (int rr = 0; rr < 2; ++rr) {
                int r = rr * 64 + srow;
                int kc = (lane & 3) ^ ((r >> 1) & 3);
                const ushort* src = Kh + (size_t)(k0 + r) * HDIM + kc * 8;
                async_copy16(src,      Ks0 + (rr * 64 + wave * 16) * 32);
                async_copy16(src + 32, Ks1 + (rr * 64 + wave * 16) * 32);
            }
            int kc = (lane & 3) ^ ((srow >> 1) & 3);
            const ushort* vsrc = Vh + (size_t)srow * NTOK + k0 + kc * 8;
            #pragma unroll
            for (int kq = 0; kq < 4; ++kq)
                async_copy16(vsrc + kq * 32, Vs + kq * 2048 + (wave * 16) * 32);
        }
        __syncthreads();

        // ---- S^T = K @ Q^T : 4 key-tiles of 32, d chained 4x16 ----
        f32x16 st[4];
        #pragma unroll
        for (int t = 0; t < 4; ++t) {
            f32x16 acc = {};
            #pragma unroll
            for (int c = 0; c < 4; ++c) {
                int row = t * 32 + ql;
                int swz = ((c & 1) * 2 + hi) ^ ((row >> 1) & 3);
                const ushort* Kbase = (c < 2) ? Ks0 : Ks1;
                bf16x8 kf = *(const bf16x8*)&Kbase[row * 32 + swz * 8];
                acc = __builtin_amdgcn_mfma_f32_32x32x16_bf16(kf, qb[c], acc, 0, 0, 0);
            }
            st[t] = acc;
        }

        // ---- p = exp2(s*SC) [raw v_exp_f32], mask only on last tile ----
        if (last) {
            #pragma unroll
            for (int t = 0; t < 4; ++t)
                #pragma unroll
                for (int r = 0; r < 16; ++r) {
                    float pv = __builtin_amdgcn_exp2f(st[t][r] * SC);
                    int key = k0 + t * 32 + (r & 3) + 8 * (r >> 2) + 4 * hi;
                    pv = (key <= qrow) ? pv : 0.f;
                    st[t][r] = pv;
                    lrun += pv;
                }
        } else {
            #pragma unroll
            for (int t = 0; t < 4; ++t)
                #pragma unroll
                for (int r = 0; r < 16; ++r) {
                    float pv = __builtin_amdgcn_exp2f(st[t][r] * SC);
                    st[t][r] = pv;
                    lrun += pv;
                }
        }

        // ---- pack + permlane exchange + PV per key-tile (no LDS for P) ----
        #pragma unroll
        for (int t = 0; t < 4; ++t) {
            unsigned int Ap[4], Bp[4];
            #pragma unroll
            for (int m = 0; m < 4; ++m) {
                Ap[m] = cvt2_bf16(st[t][4 * m],     st[t][4 * m + 1]);
                Bp[m] = cvt2_bf16(st[t][4 * m + 2], st[t][4 * m + 3]);
            }
            #pragma unroll
            for (int kc = 0; kc < 2; ++kc) {
                unsigned int xa = Ap[2 * kc], ya = Ap[2 * kc + 1];
                unsigned int xb = Bp[2 * kc], yb = Bp[2 * kc + 1];
                permlane32_swap(xa, ya);   // xa' -> w0 (keys kc*16+8hi+{0,1}), ya' -> w2 (+{4,5})
                permlane32_swap(xb, yb);   // xb' -> w1 (+{2,3}),               yb' -> w3 (+{6,7})
                u32x4 pw; pw[0] = xa; pw[1] = xb; pw[2] = ya; pw[3] = yb;
                bf16x8 pf = __builtin_bit_cast(bf16x8, pw);
                #pragma unroll
                for (int dt = 0; dt < 2; ++dt) {
                    int row = dt * 32 + ql;
                    int swz = (kc * 2 + hi) ^ ((row >> 1) & 3);
                    bf16x8 vf = *(const bf16x8*)&Vs[t * 2048 + row * 32 + swz * 8];
                    o2[dt] = __builtin_amdgcn_mfma_f32_32x32x16_bf16(vf, pf, o2[dt], 0, 0, 0);
                }
            }
        }
        __syncthreads();
    }

    // ---- epilogue ----
    lrun += __shfl_xor(lrun, 32, 64);
    float inv = 1.f / lrun;
    size_t rbase = ((size_t)(b * SEQ + qrow)) * EMB + h * HDIM;
    #pragma unroll
    for (int dt = 0; dt < 2; ++dt)
        #pragma unroll
        for (int m = 0; m < 4; ++m) {
            int d = dt * 32 + 8 * m + 4 * hi;
            ushort4 s4;
            s4.x = f2bf(o2[dt][4 * m]     * inv);
            s4.y = f2bf(o2[dt][4 * m + 1] * inv);
            s4.z = f2bf(o2[dt][4 * m + 2] * inv);
            s4.w = f2bf(o2[dt][4 * m + 3] * inv);
            *(ushort4*)(Yb + rbase + d) = s4;
        }
}

__global__ __launch_bounds__(256, 2) void attn(
    const ushort* __restrict__ Qb, const ushort* __restrict__ Kb,
    const ushort* __restrict__ Vtx, ushort* __restrict__ Yb)
{
    __shared__ ushort Ks0[128 * 32];   // K d=0..31
    __shared__ ushort Ks1[128 * 32];   // K d=32..63
    __shared__ ushort Vs[4 * 64 * 32]; // V^T key-quarters
    const int lane = threadIdx.x & 63;
    const int wave = threadIdx.x >> 6;
    const int bh   = blockIdx.x & 63;   // b*16+h ; same-bh blocks share an XCD
    const int pr   = blockIdx.x >> 6;   // q-tile pair {15-pr, pr}: 17 k-tiles/block

    const int b = bh >> 4, h = bh & 15;
    const ushort* Qh = Qb + (size_t)bh * SEQ * HDIM;
    const ushort* Kh = Kb + (size_t)bh * SEQ * HDIM;
    const ushort* Vh = Vtx + (size_t)(h * HDIM) * NTOK + b * SEQ;

    attn_qtile(15 - pr, b, h, lane, wave, Qh, Kh, Vh, Yb, Ks0, Ks1, Vs);
    __syncthreads();
    attn_qtile(pr,      b, h, lane, wave, Qh, Kh, Vh, Yb, Ks0, Ks1, Vs);
}

extern "C" void kernel_launch(void* const* d_in, const int* in_sizes, int n_in,
                              void* d_out, int out_size, void* d_ws, size_t ws_size,
                              hipStream_t stream) {
    const float* x      = (const float*)d_in[0];
    const float* W_qkv  = (const float*)d_in[1];
    const float* b_qkv  = (const float*)d_in[2];
    const float* W_proj = (const float*)d_in[3];
    const float* b_proj = (const float*)d_in[4];
    float* out = (float*)d_out;

    ushort* ws     = (ushort*)d_ws;
    ushort* Xb     = ws;                 // reused as Yb after attn inputs ready
    ushort* Yb     = ws;
    ushort* Wqkvb  = ws + 8388608;
    ushort* Wprojb = ws + 11534336;
    ushort* Qb     = ws + 12582912;
    ushort* Kb     = ws + 20971520;
    ushort* Vtx    = ws + 29360128;      // [1024 channels][8192 tokens]

    cvt_f32_bf16<<<8192, 256, 0, stream>>>((const float4*)x,      Xb,     2097152);
    cvt_f32_bf16<<<3072, 256, 0, stream>>>((const float4*)W_qkv,  Wqkvb,  786432);
    cvt_f32_bf16<<<1024, 256, 0, stream>>>((const float4*)W_proj, Wprojb, 262144);

    gemm_qk<<<dim3(64, 16), 256, 0, stream>>>(Xb, Wqkvb, b_qkv, Qb, Kb);
    gemm_vt<<<dim3(8, 64), 256, 0, stream>>>(Wqkvb + (size_t)2048 * EMB, Xb,
                                             b_qkv + 2048, Vtx);
    attn<<<512, 256, 0, stream>>>(Qb, Kb, Vtx, Yb);
    gemm_proj<<<dim3(64, 8), 256, 0, stream>>>(Yb, Wprojb, b_proj, out);
}

// Round 11
// 239.778 us; speedup vs baseline: 1.4511x; 1.0204x over previous
//
#include <hip/hip_runtime.h>
#include <hip/hip_bf16.h>

typedef __attribute__((ext_vector_type(4))) float f32x4;
typedef __attribute__((ext_vector_type(16))) float f32x16;
typedef __attribute__((ext_vector_type(8))) __bf16 bf16x8;
typedef __attribute__((ext_vector_type(4))) unsigned int u32x4;

#define EMB 1024
#define NHEAD 16
#define HDIM 64
#define SEQ 2048
#define BATCH 4
#define NTOK 8192

__device__ __forceinline__ unsigned short f2bf(float f) {
    unsigned int u = __builtin_bit_cast(unsigned int, f);
    u = (u + 0x7fffu + ((u >> 16) & 1u)) >> 16;
    return (unsigned short)u;
}

// packed 2x f32->bf16 ; compiler lowers the cast pair to v_cvt_pk_bf16_f32
__device__ __forceinline__ unsigned int cvt2_bf16(float lo, float hi) {
    unsigned short a = __builtin_bit_cast(unsigned short, (__bf16)lo);
    unsigned short b = __builtin_bit_cast(unsigned short, (__bf16)hi);
    return (unsigned int)a | ((unsigned int)b << 16);
}

// v_permlane32_swap_b32 vdst, vsrc — swaps vdst's HIGH half with vsrc's LOW half:
//   vdst'[l] = (l<32) ? vdst[l] : vsrc[l-32]
//   vsrc'[l] = (l<32) ? vdst[l+32] : vsrc[l]
__device__ __forceinline__ void permlane32_swap(unsigned int &x, unsigned int &y) {
    asm volatile("v_permlane32_swap_b32 %0, %1" : "+v"(x), "+v"(y));
}

__device__ __forceinline__ void async_copy16(const ushort* g, ushort* l) {
    __builtin_amdgcn_global_load_lds(
        (const __attribute__((address_space(1))) void*)g,
        (__attribute__((address_space(3))) void*)l,
        16, 0, 0);
}

// ---------------- fused fp32 -> bf16 convert (x, W_qkv, W_proj in one launch) ----------------
#define XN4 2097152
#define WQN4 786432
#define WPN4 262144
__global__ void cvt_all(const float4* __restrict__ x, const float4* __restrict__ wqkv,
                        const float4* __restrict__ wproj,
                        ushort* __restrict__ xb, ushort* __restrict__ wqkvb,
                        ushort* __restrict__ wprojb) {
    int i = blockIdx.x * 256 + threadIdx.x;
    const float4* src; ushort* dst; int k;
    if (i < XN4)                { src = x;     dst = xb;     k = i; }
    else if (i < XN4 + WQN4)    { src = wqkv;  dst = wqkvb;  k = i - XN4; }
    else if (i < XN4 + WQN4 + WPN4) { src = wproj; dst = wprojb; k = i - XN4 - WQN4; }
    else return;
    float4 v = src[k];
    ushort4 o;
    o.x = f2bf(v.x); o.y = f2bf(v.y); o.z = f2bf(v.z); o.w = f2bf(v.w);
    ((ushort4*)dst)[k] = o;
}

// ================= 128x128-tile GEMM core, BK=64 (r6, verified) ======
#define GEMM_STAGE64(Asrc, Bsrc, m0, n0, kt)                                      \
    {                                                                             \
        _Pragma("unroll")                                                         \
        for (int j = 0; j < 2; ++j) {                                             \
            int row = wave * 32 + j * 16 + (lane >> 2);                           \
            int kc  = (lane & 3) ^ ((row >> 1) & 3);                              \
            const ushort* asrc = Asrc + (size_t)(m0 + row) * EMB + kt + kc * 8;   \
            const ushort* bsrc = Bsrc + (size_t)(n0 + row) * EMB + kt + kc * 8;   \
            async_copy16(asrc,      As0 + (wave * 32 + j * 16) * 32);             \
            async_copy16(asrc + 32, As1 + (wave * 32 + j * 16) * 32);             \
            async_copy16(bsrc,      Bs0 + (wave * 32 + j * 16) * 32);             \
            async_copy16(bsrc + 32, Bs1 + (wave * 32 + j * 16) * 32);             \
        }                                                                         \
    }

#define GEMM_BODY64(Asrc, Bsrc, m0, n0)                                           \
    f32x4 acc[4][4] = {};                                                         \
    for (int kt = 0; kt < EMB; kt += 64) {                                        \
        GEMM_STAGE64(Asrc, Bsrc, m0, n0, kt)                                      \
        __syncthreads();                                                          \
        _Pragma("unroll")                                                         \
        for (int hf = 0; hf < 2; ++hf) {                                          \
            const ushort* Ah = hf ? As1 : As0;                                    \
            const ushort* Bh = hf ? Bs1 : Bs0;                                    \
            bf16x8 a[4], b[4];                                                    \
            _Pragma("unroll")                                                     \
            for (int i = 0; i < 4; ++i) {                                         \
                int r = wm + i * 16 + col;                                        \
                a[i] = *(const bf16x8*)&Ah[r * 32 + (quad ^ ((r >> 1) & 3)) * 8]; \
                int c = wn + i * 16 + col;                                        \
                b[i] = *(const bf16x8*)&Bh[c * 32 + (quad ^ ((c >> 1) & 3)) * 8]; \
            }                                                                     \
            _Pragma("unroll")                                                     \
            for (int i = 0; i < 4; ++i)                                           \
                _Pragma("unroll")                                                 \
                for (int j = 0; j < 4; ++j)                                       \
                    acc[i][j] = __builtin_amdgcn_mfma_f32_16x16x32_bf16(          \
                        a[i], b[j], acc[i][j], 0, 0, 0);                          \
        }                                                                         \
        __syncthreads();                                                          \
    }

// ---------------- QK GEMM, 256x256 tile: X[8192,1024] @ Wqk[2048,1024]^T -> Q,K ----
// r10: 8 waves (2M x 4N), per-wave 128x64 output (acc[8][4]), BK=64 double-buffered
// (128KB dynamic LDS), prefetch-next-tile-at-top + single __syncthreads per K-tile.
// Grid 8x32 = 256 blocks = 1/CU. Staging/read algebra identical to verified
// GEMM_STAGE64 (8 waves cover 256 rows: wave*32+j*16+(lane>>2)).
__global__ __launch_bounds__(512, 2) void gemm_qk(
    const ushort* __restrict__ A,
    const ushort* __restrict__ W,
    const float*  __restrict__ bias,
    ushort* __restrict__ Qb, ushort* __restrict__ Kb)
{
    extern __shared__ ushort lds[];   // 2 bufs x [As0,As1,Bs0,Bs1] x 256x32 ushorts
    const int tid  = threadIdx.x;
    const int lane = tid & 63;
    const int wave = tid >> 6;
    const int col  = lane & 15;
    const int quad = lane >> 4;
    const int n0 = blockIdx.x * 256;
    const int m0 = blockIdx.y * 256;
    const int wm = (wave >> 2) * 128;
    const int wn = (wave & 3) * 64;

    f32x4 acc[8][4] = {};

    // stage unit: buf base b_, K-offset kt
#define QK_STAGE(b_, kt)                                                          \
    {                                                                             \
        _Pragma("unroll")                                                         \
        for (int j = 0; j < 2; ++j) {                                             \
            int row = wave * 32 + j * 16 + (lane >> 2);                           \
            int kc  = (lane & 3) ^ ((row >> 1) & 3);                              \
            const ushort* asrc = A + (size_t)(m0 + row) * EMB + kt + kc * 8;      \
            const ushort* bsrc = W + (size_t)(n0 + row) * EMB + kt + kc * 8;      \
            ushort* db = (b_) + (wave * 32 + j * 16) * 32;                        \
            async_copy16(asrc,      db);                                          \
            async_copy16(asrc + 32, db + 8192);                                   \
            async_copy16(bsrc,      db + 16384);                                  \
            async_copy16(bsrc + 32, db + 24576);                                  \
        }                                                                         \
    }

    QK_STAGE(lds, 0)
    __syncthreads();

    for (int ki = 0; ki < 16; ++ki) {
        const int cur = ki & 1;
        if (ki < 15) QK_STAGE(lds + (cur ^ 1) * 32768, (ki + 1) * 64)

        const ushort* buf = lds + cur * 32768;
        const ushort* A0 = buf;
        const ushort* A1 = buf + 8192;
        const ushort* B0 = buf + 16384;
        const ushort* B1 = buf + 24576;

        bf16x8 b0[4], b1[4];
        #pragma unroll
        for (int j = 0; j < 4; ++j) {
            int c = wn + j * 16 + col;
            int swz = (quad ^ ((c >> 1) & 3)) * 8;
            b0[j] = *(const bf16x8*)&B0[c * 32 + swz];
            b1[j] = *(const bf16x8*)&B1[c * 32 + swz];
        }
        #pragma unroll
        for (int i = 0; i < 8; ++i) {
            int r = wm + i * 16 + col;
            int swz = (quad ^ ((r >> 1) & 3)) * 8;
            bf16x8 a0 = *(const bf16x8*)&A0[r * 32 + swz];
            bf16x8 a1 = *(const bf16x8*)&A1[r * 32 + swz];
            #pragma unroll
            for (int j = 0; j < 4; ++j) {
                acc[i][j] = __builtin_amdgcn_mfma_f32_16x16x32_bf16(a0, b0[j], acc[i][j], 0, 0, 0);
                acc[i][j] = __builtin_amdgcn_mfma_f32_16x16x32_bf16(a1, b1[j], acc[i][j], 0, 0, 0);
            }
        }
        __syncthreads();
    }
#undef QK_STAGE

    #pragma unroll
    for (int i = 0; i < 8; ++i)
        #pragma unroll
        for (int j = 0; j < 4; ++j)
            #pragma unroll
            for (int r = 0; r < 4; ++r) {
                int m = m0 + wm + i * 16 + quad * 4 + r;
                int n = n0 + wn + j * 16 + col;
                float v = acc[i][j][r] + bias[n];
                unsigned short bv = f2bf(v);
                int e = n & 1023;
                int h = e >> 6, d = e & 63;
                int b = m >> 11, s = m & 2047;
                size_t bh = (size_t)(b * NHEAD + h);
                if (n < 1024) Qb[(bh * SEQ + s) * HDIM + d] = bv;
                else          Kb[(bh * SEQ + s) * HDIM + d] = bv;
            }
}

// ---------------- V^T GEMM: Wv[1024,1024] @ X^T -> Vtx[1024,8192] + bias(m) ----------------
__global__ __launch_bounds__(256) void gemm_vt(
    const ushort* __restrict__ Wv,
    const ushort* __restrict__ X,
    const float*  __restrict__ bias,
    ushort* __restrict__ Vtx)
{
    __shared__ ushort As0[128 * 32];
    __shared__ ushort As1[128 * 32];
    __shared__ ushort Bs0[128 * 32];
    __shared__ ushort Bs1[128 * 32];
    const int tid  = threadIdx.x;
    const int lane = tid & 63;
    const int wave = tid >> 6;
    const int col  = lane & 15;
    const int quad = lane >> 4;
    const int m0 = blockIdx.x * 128;   // channel
    const int n0 = blockIdx.y * 128;   // token
    const int wm = (wave >> 1) * 64;
    const int wn = (wave & 1) * 64;

    GEMM_BODY64(Wv, X, m0, n0)

    #pragma unroll
    for (int i = 0; i < 4; ++i)
        #pragma unroll
        for (int j = 0; j < 4; ++j)
            #pragma unroll
            for (int r = 0; r < 4; ++r) {
                int m = m0 + wm + i * 16 + quad * 4 + r;
                int n = n0 + wn + j * 16 + col;
                Vtx[(size_t)m * NTOK + n] = f2bf(acc[i][j][r] + bias[m]);
            }
}

// ---------------- Output proj + bias -> fp32 out ----------------
__global__ __launch_bounds__(256) void gemm_proj(
    const ushort* __restrict__ A,
    const ushort* __restrict__ W,
    const float*  __restrict__ bias,
    float* __restrict__ out)
{
    __shared__ ushort As0[128 * 32];
    __shared__ ushort As1[128 * 32];
    __shared__ ushort Bs0[128 * 32];
    __shared__ ushort Bs1[128 * 32];
    const int tid  = threadIdx.x;
    const int lane = tid & 63;
    const int wave = tid >> 6;
    const int col  = lane & 15;
    const int quad = lane >> 4;
    const int m0 = blockIdx.x * 128;
    const int n0 = blockIdx.y * 128;
    const int wm = (wave >> 1) * 64;
    const int wn = (wave & 1) * 64;

    GEMM_BODY64(A, W, m0, n0)

    #pragma unroll
    for (int i = 0; i < 4; ++i)
        #pragma unroll
        for (int j = 0; j < 4; ++j)
            #pragma unroll
            for (int r = 0; r < 4; ++r) {
                int m = m0 + wm + i * 16 + quad * 4 + r;
                int n = n0 + wn + j * 16 + col;
                out[(size_t)m * EMB + n] = acc[i][j][r] + bias[n];
            }
}

// ---------------- Flash attention: 32x32 MFMA + permlane P-exchange (r10, verified) ----
__device__ __forceinline__ void attn_qtile(
    int qt, int b, int h, int lane, int wave,
    const ushort* __restrict__ Qh, const ushort* __restrict__ Kh,
    const ushort* __restrict__ Vh, ushort* __restrict__ Yb,
    ushort* __restrict__ Ks0, ushort* __restrict__ Ks1, ushort* __restrict__ Vs)
{
    const int ql = lane & 31;
    const int hi = lane >> 5;
    const int q0 = qt * 128 + wave * 32;
    const int qrow = q0 + ql;
    const float SC = 0.125f * 1.44269504f;

    bf16x8 qb[4];
    #pragma unroll
    for (int c = 0; c < 4; ++c)
        qb[c] = *(const bf16x8*)(Qh + (size_t)qrow * HDIM + c * 16 + hi * 8);

    f32x16 o2[2] = {};
    float lrun = 0.f;

    const int nk = qt + 1;
    for (int kt = 0; kt < nk; ++kt) {
        const int k0 = kt * 128;
        const bool last = (kt == nk - 1);

        {
            int srow = wave * 16 + (lane >> 2);
            #pragma unroll
            for (int rr = 0; rr < 2; ++rr) {
                int r = rr * 64 + srow;
                int kc = (lane & 3) ^ ((r >> 1) & 3);
                const ushort* src = Kh + (size_t)(k0 + r) * HDIM + kc * 8;
                async_copy16(src,      Ks0 + (rr * 64 + wave * 16) * 32);
                async_copy16(src + 32, Ks1 + (rr * 64 + wave * 16) * 32);
            }
            int kc = (lane & 3) ^ ((srow >> 1) & 3);
            const ushort* vsrc = Vh + (size_t)srow * NTOK + k0 + kc * 8;
            #pragma unroll
            for (int kq = 0; kq < 4; ++kq)
                async_copy16(vsrc + kq * 32, Vs + kq * 2048 + (wave * 16) * 32);
        }
        __syncthreads();

        f32x16 st[4];
        #pragma unroll
        for (int t = 0; t < 4; ++t) {
            f32x16 acc = {};
            #pragma unroll
            for (int c = 0; c < 4; ++c) {
                int row = t * 32 + ql;
                int swz = ((c & 1) * 2 + hi) ^ ((row >> 1) & 3);
                const ushort* Kbase = (c < 2) ? Ks0 : Ks1;
                bf16x8 kf = *(const bf16x8*)&Kbase[row * 32 + swz * 8];
                acc = __builtin_amdgcn_mfma_f32_32x32x16_bf16(kf, qb[c], acc, 0, 0, 0);
            }
            st[t] = acc;
        }

        if (last) {
            #pragma unroll
            for (int t = 0; t < 4; ++t)
                #pragma unroll
                for (int r = 0; r < 16; ++r) {
                    float pv = __builtin_amdgcn_exp2f(st[t][r] * SC);
                    int key = k0 + t * 32 + (r & 3) + 8 * (r >> 2) + 4 * hi;
                    pv = (key <= qrow) ? pv : 0.f;
                    st[t][r] = pv;
                    lrun += pv;
                }
        } else {
            #pragma unroll
            for (int t = 0; t < 4; ++t)
                #pragma unroll
                for (int r = 0; r < 16; ++r) {
                    float pv = __builtin_amdgcn_exp2f(st[t][r] * SC);
                    st[t][r] = pv;
                    lrun += pv;
                }
        }

        #pragma unroll
        for (int t = 0; t < 4; ++t) {
            unsigned int Ap[4], Bp[4];
            #pragma unroll
            for (int m = 0; m < 4; ++m) {
                Ap[m] = cvt2_bf16(st[t][4 * m],     st[t][4 * m + 1]);
                Bp[m] = cvt2_bf16(st[t][4 * m + 2], st[t][4 * m + 3]);
            }
            #pragma unroll
            for (int kc = 0; kc < 2; ++kc) {
                unsigned int xa = Ap[2 * kc], ya = Ap[2 * kc + 1];
                unsigned int xb = Bp[2 * kc], yb = Bp[2 * kc + 1];
                permlane32_swap(xa, ya);
                permlane32_swap(xb, yb);
                u32x4 pw; pw[0] = xa; pw[1] = xb; pw[2] = ya; pw[3] = yb;
                bf16x8 pf = __builtin_bit_cast(bf16x8, pw);
                #pragma unroll
                for (int dt = 0; dt < 2; ++dt) {
                    int row = dt * 32 + ql;
                    int swz = (kc * 2 + hi) ^ ((row >> 1) & 3);
                    bf16x8 vf = *(const bf16x8*)&Vs[t * 2048 + row * 32 + swz * 8];
                    o2[dt] = __builtin_amdgcn_mfma_f32_32x32x16_bf16(vf, pf, o2[dt], 0, 0, 0);
                }
            }
        }
        __syncthreads();
    }

    lrun += __shfl_xor(lrun, 32, 64);
    float inv = 1.f / lrun;
    size_t rbase = ((size_t)(b * SEQ + qrow)) * EMB + h * HDIM;
    #pragma unroll
    for (int dt = 0; dt < 2; ++dt)
        #pragma unroll
        for (int m = 0; m < 4; ++m) {
            int d = dt * 32 + 8 * m + 4 * hi;
            ushort4 s4;
            s4.x = f2bf(o2[dt][4 * m]     * inv);
            s4.y = f2bf(o2[dt][4 * m + 1] * inv);
            s4.z = f2bf(o2[dt][4 * m + 2] * inv);
            s4.w = f2bf(o2[dt][4 * m + 3] * inv);
            *(ushort4*)(Yb + rbase + d) = s4;
        }
}

__global__ __launch_bounds__(256, 2) void attn(
    const ushort* __restrict__ Qb, const ushort* __restrict__ Kb,
    const ushort* __restrict__ Vtx, ushort* __restrict__ Yb)
{
    __shared__ ushort Ks0[128 * 32];   // K d=0..31
    __shared__ ushort Ks1[128 * 32];   // K d=32..63
    __shared__ ushort Vs[4 * 64 * 32]; // V^T key-quarters
    const int lane = threadIdx.x & 63;
    const int wave = threadIdx.x >> 6;
    const int bh   = blockIdx.x & 63;   // b*16+h ; same-bh blocks share an XCD
    const int pr   = blockIdx.x >> 6;   // q-tile pair {15-pr, pr}: 17 k-tiles/block

    const int b = bh >> 4, h = bh & 15;
    const ushort* Qh = Qb + (size_t)bh * SEQ * HDIM;
    const ushort* Kh = Kb + (size_t)bh * SEQ * HDIM;
    const ushort* Vh = Vtx + (size_t)(h * HDIM) * NTOK + b * SEQ;

    attn_qtile(15 - pr, b, h, lane, wave, Qh, Kh, Vh, Yb, Ks0, Ks1, Vs);
    __syncthreads();
    attn_qtile(pr,      b, h, lane, wave, Qh, Kh, Vh, Yb, Ks0, Ks1, Vs);
}

extern "C" void kernel_launch(void* const* d_in, const int* in_sizes, int n_in,
                              void* d_out, int out_size, void* d_ws, size_t ws_size,
                              hipStream_t stream) {
    const float* x      = (const float*)d_in[0];
    const float* W_qkv  = (const float*)d_in[1];
    const float* b_qkv  = (const float*)d_in[2];
    const float* W_proj = (const float*)d_in[3];
    const float* b_proj = (const float*)d_in[4];
    float* out = (float*)d_out;

    ushort* ws     = (ushort*)d_ws;
    ushort* Xb     = ws;                 // reused as Yb after attn inputs ready
    ushort* Yb     = ws;
    ushort* Wqkvb  = ws + 8388608;
    ushort* Wprojb = ws + 11534336;
    ushort* Qb     = ws + 12582912;
    ushort* Kb     = ws + 20971520;
    ushort* Vtx    = ws + 29360128;      // [1024 channels][8192 tokens]

    hipFuncSetAttribute((const void*)gemm_qk,
                        hipFuncAttributeMaxDynamicSharedMemorySize, 131072);

    cvt_all<<<12288, 256, 0, stream>>>((const float4*)x, (const float4*)W_qkv,
                                       (const float4*)W_proj, Xb, Wqkvb, Wprojb);

    gemm_qk<<<dim3(8, 32), 512, 131072, stream>>>(Xb, Wqkvb, b_qkv, Qb, Kb);
    gemm_vt<<<dim3(8, 64), 256, 0, stream>>>(Wqkvb + (size_t)2048 * EMB, Xb,
                                             b_qkv + 2048, Vtx);
    attn<<<512, 256, 0, stream>>>(Qb, Kb, Vtx, Yb);
    gemm_proj<<<dim3(64, 8), 256, 0, stream>>>(Yb, Wprojb, b_proj, out);
}

// Round 12
// 238.547 us; speedup vs baseline: 1.4586x; 1.0052x over previous
//
#include <hip/hip_runtime.h>
#include <hip/hip_bf16.h>

typedef __attribute__((ext_vector_type(4))) float f32x4;
typedef __attribute__((ext_vector_type(16))) float f32x16;
typedef __attribute__((ext_vector_type(8))) __bf16 bf16x8;
typedef __attribute__((ext_vector_type(4))) unsigned int u32x4;

#define EMB 1024
#define NHEAD 16
#define HDIM 64
#define SEQ 2048
#define BATCH 4
#define NTOK 8192

__device__ __forceinline__ unsigned short f2bf(float f) {
    unsigned int u = __builtin_bit_cast(unsigned int, f);
    u = (u + 0x7fffu + ((u >> 16) & 1u)) >> 16;
    return (unsigned short)u;
}

// packed 2x f32->bf16 ; compiler lowers the cast pair to v_cvt_pk_bf16_f32
__device__ __forceinline__ unsigned int cvt2_bf16(float lo, float hi) {
    unsigned short a = __builtin_bit_cast(unsigned short, (__bf16)lo);
    unsigned short b = __builtin_bit_cast(unsigned short, (__bf16)hi);
    return (unsigned int)a | ((unsigned int)b << 16);
}

// v_permlane32_swap_b32 vdst, vsrc — swaps vdst's HIGH half with vsrc's LOW half:
//   vdst'[l] = (l<32) ? vdst[l] : vsrc[l-32]
//   vsrc'[l] = (l<32) ? vdst[l+32] : vsrc[l]
__device__ __forceinline__ void permlane32_swap(unsigned int &x, unsigned int &y) {
    asm volatile("v_permlane32_swap_b32 %0, %1" : "+v"(x), "+v"(y));
}

__device__ __forceinline__ void async_copy16(const ushort* g, ushort* l) {
    __builtin_amdgcn_global_load_lds(
        (const __attribute__((address_space(1))) void*)g,
        (__attribute__((address_space(3))) void*)l,
        16, 0, 0);
}

// ---------------- fused fp32 -> bf16 convert (x, W_qkv, W_proj in one launch) ----------------
#define XN4 2097152
#define WQN4 786432
#define WPN4 262144
__global__ void cvt_all(const float4* __restrict__ x, const float4* __restrict__ wqkv,
                        const float4* __restrict__ wproj,
                        ushort* __restrict__ xb, ushort* __restrict__ wqkvb,
                        ushort* __restrict__ wprojb) {
    int i = blockIdx.x * 256 + threadIdx.x;
    const float4* src; ushort* dst; int k;
    if (i < XN4)                { src = x;     dst = xb;     k = i; }
    else if (i < XN4 + WQN4)    { src = wqkv;  dst = wqkvb;  k = i - XN4; }
    else if (i < XN4 + WQN4 + WPN4) { src = wproj; dst = wprojb; k = i - XN4 - WQN4; }
    else return;
    float4 v = src[k];
    ushort4 o;
    o.x = f2bf(v.x); o.y = f2bf(v.y); o.z = f2bf(v.z); o.w = f2bf(v.w);
    ((ushort4*)dst)[k] = o;
}

// ================= 128x128-tile GEMM core, BK=64 (r6, verified) ======
#define GEMM_STAGE64(Asrc, Bsrc, m0, n0, kt)                                      \
    {                                                                             \
        _Pragma("unroll")                                                         \
        for (int j = 0; j < 2; ++j) {                                             \
            int row = wave * 32 + j * 16 + (lane >> 2);                           \
            int kc  = (lane & 3) ^ ((row >> 1) & 3);                              \
            const ushort* asrc = Asrc + (size_t)(m0 + row) * EMB + kt + kc * 8;   \
            const ushort* bsrc = Bsrc + (size_t)(n0 + row) * EMB + kt + kc * 8;   \
            async_copy16(asrc,      As0 + (wave * 32 + j * 16) * 32);             \
            async_copy16(asrc + 32, As1 + (wave * 32 + j * 16) * 32);             \
            async_copy16(bsrc,      Bs0 + (wave * 32 + j * 16) * 32);             \
            async_copy16(bsrc + 32, Bs1 + (wave * 32 + j * 16) * 32);             \
        }                                                                         \
    }

#define GEMM_BODY64(Asrc, Bsrc, m0, n0)                                           \
    f32x4 acc[4][4] = {};                                                         \
    for (int kt = 0; kt < EMB; kt += 64) {                                        \
        GEMM_STAGE64(Asrc, Bsrc, m0, n0, kt)                                      \
        __syncthreads();                                                          \
        _Pragma("unroll")                                                         \
        for (int hf = 0; hf < 2; ++hf) {                                          \
            const ushort* Ah = hf ? As1 : As0;                                    \
            const ushort* Bh = hf ? Bs1 : Bs0;                                    \
            bf16x8 a[4], b[4];                                                    \
            _Pragma("unroll")                                                     \
            for (int i = 0; i < 4; ++i) {                                         \
                int r = wm + i * 16 + col;                                        \
                a[i] = *(const bf16x8*)&Ah[r * 32 + (quad ^ ((r >> 1) & 3)) * 8]; \
                int c = wn + i * 16 + col;                                        \
                b[i] = *(const bf16x8*)&Bh[c * 32 + (quad ^ ((c >> 1) & 3)) * 8]; \
            }                                                                     \
            _Pragma("unroll")                                                     \
            for (int i = 0; i < 4; ++i)                                           \
                _Pragma("unroll")                                                 \
                for (int j = 0; j < 4; ++j)                                       \
                    acc[i][j] = __builtin_amdgcn_mfma_f32_16x16x32_bf16(          \
                        a[i], b[j], acc[i][j], 0, 0, 0);                          \
        }                                                                         \
        __syncthreads();                                                          \
    }

// ---------------- QK GEMM, 256x256 tile: X[8192,1024] @ Wqk[2048,1024]^T -> Q,K ----
__global__ __launch_bounds__(512, 2) void gemm_qk(
    const ushort* __restrict__ A,
    const ushort* __restrict__ W,
    const float*  __restrict__ bias,
    ushort* __restrict__ Qb, ushort* __restrict__ Kb)
{
    extern __shared__ ushort lds[];   // 2 bufs x [As0,As1,Bs0,Bs1] x 256x32 ushorts
    const int tid  = threadIdx.x;
    const int lane = tid & 63;
    const int wave = tid >> 6;
    const int col  = lane & 15;
    const int quad = lane >> 4;
    const int n0 = blockIdx.x * 256;
    const int m0 = blockIdx.y * 256;
    const int wm = (wave >> 2) * 128;
    const int wn = (wave & 3) * 64;

    f32x4 acc[8][4] = {};

#define QK_STAGE(b_, kt)                                                          \
    {                                                                             \
        _Pragma("unroll")                                                         \
        for (int j = 0; j < 2; ++j) {                                             \
            int row = wave * 32 + j * 16 + (lane >> 2);                           \
            int kc  = (lane & 3) ^ ((row >> 1) & 3);                              \
            const ushort* asrc = A + (size_t)(m0 + row) * EMB + kt + kc * 8;      \
            const ushort* bsrc = W + (size_t)(n0 + row) * EMB + kt + kc * 8;      \
            ushort* db = (b_) + (wave * 32 + j * 16) * 32;                        \
            async_copy16(asrc,      db);                                          \
            async_copy16(asrc + 32, db + 8192);                                   \
            async_copy16(bsrc,      db + 16384);                                  \
            async_copy16(bsrc + 32, db + 24576);                                  \
        }                                                                         \
    }

    QK_STAGE(lds, 0)
    __syncthreads();

    for (int ki = 0; ki < 16; ++ki) {
        const int cur = ki & 1;
        if (ki < 15) QK_STAGE(lds + (cur ^ 1) * 32768, (ki + 1) * 64)

        const ushort* buf = lds + cur * 32768;
        const ushort* A0 = buf;
        const ushort* A1 = buf + 8192;
        const ushort* B0 = buf + 16384;
        const ushort* B1 = buf + 24576;

        bf16x8 b0[4], b1[4];
        #pragma unroll
        for (int j = 0; j < 4; ++j) {
            int c = wn + j * 16 + col;
            int swz = (quad ^ ((c >> 1) & 3)) * 8;
            b0[j] = *(const bf16x8*)&B0[c * 32 + swz];
            b1[j] = *(const bf16x8*)&B1[c * 32 + swz];
        }
        #pragma unroll
        for (int i = 0; i < 8; ++i) {
            int r = wm + i * 16 + col;
            int swz = (quad ^ ((r >> 1) & 3)) * 8;
            bf16x8 a0 = *(const bf16x8*)&A0[r * 32 + swz];
            bf16x8 a1 = *(const bf16x8*)&A1[r * 32 + swz];
            #pragma unroll
            for (int j = 0; j < 4; ++j) {
                acc[i][j] = __builtin_amdgcn_mfma_f32_16x16x32_bf16(a0, b0[j], acc[i][j], 0, 0, 0);
                acc[i][j] = __builtin_amdgcn_mfma_f32_16x16x32_bf16(a1, b1[j], acc[i][j], 0, 0, 0);
            }
        }
        __syncthreads();
    }
#undef QK_STAGE

    #pragma unroll
    for (int i = 0; i < 8; ++i)
        #pragma unroll
        for (int j = 0; j < 4; ++j)
            #pragma unroll
            for (int r = 0; r < 4; ++r) {
                int m = m0 + wm + i * 16 + quad * 4 + r;
                int n = n0 + wn + j * 16 + col;
                float v = acc[i][j][r] + bias[n];
                unsigned short bv = f2bf(v);
                int e = n & 1023;
                int h = e >> 6, d = e & 63;
                int b = m >> 11, s = m & 2047;
                size_t bh = (size_t)(b * NHEAD + h);
                if (n < 1024) Qb[(bh * SEQ + s) * HDIM + d] = bv;
                else          Kb[(bh * SEQ + s) * HDIM + d] = bv;
            }
}

// ---------------- V^T GEMM: Wv[1024,1024] @ X^T -> Vtx[1024,8192] + bias(m) ----------------
__global__ __launch_bounds__(256) void gemm_vt(
    const ushort* __restrict__ Wv,
    const ushort* __restrict__ X,
    const float*  __restrict__ bias,
    ushort* __restrict__ Vtx)
{
    __shared__ ushort As0[128 * 32];
    __shared__ ushort As1[128 * 32];
    __shared__ ushort Bs0[128 * 32];
    __shared__ ushort Bs1[128 * 32];
    const int tid  = threadIdx.x;
    const int lane = tid & 63;
    const int wave = tid >> 6;
    const int col  = lane & 15;
    const int quad = lane >> 4;
    const int m0 = blockIdx.x * 128;   // channel
    const int n0 = blockIdx.y * 128;   // token
    const int wm = (wave >> 1) * 64;
    const int wn = (wave & 1) * 64;

    GEMM_BODY64(Wv, X, m0, n0)

    #pragma unroll
    for (int i = 0; i < 4; ++i)
        #pragma unroll
        for (int j = 0; j < 4; ++j)
            #pragma unroll
            for (int r = 0; r < 4; ++r) {
                int m = m0 + wm + i * 16 + quad * 4 + r;
                int n = n0 + wn + j * 16 + col;
                Vtx[(size_t)m * NTOK + n] = f2bf(acc[i][j][r] + bias[m]);
            }
}

// ---------------- Output proj + bias -> fp32 out ----------------
__global__ __launch_bounds__(256) void gemm_proj(
    const ushort* __restrict__ A,
    const ushort* __restrict__ W,
    const float*  __restrict__ bias,
    float* __restrict__ out)
{
    __shared__ ushort As0[128 * 32];
    __shared__ ushort As1[128 * 32];
    __shared__ ushort Bs0[128 * 32];
    __shared__ ushort Bs1[128 * 32];
    const int tid  = threadIdx.x;
    const int lane = tid & 63;
    const int wave = tid >> 6;
    const int col  = lane & 15;
    const int quad = lane >> 4;
    const int m0 = blockIdx.x * 128;
    const int n0 = blockIdx.y * 128;
    const int wm = (wave >> 1) * 64;
    const int wn = (wave & 1) * 64;

    GEMM_BODY64(A, W, m0, n0)

    #pragma unroll
    for (int i = 0; i < 4; ++i)
        #pragma unroll
        for (int j = 0; j < 4; ++j)
            #pragma unroll
            for (int r = 0; r < 4; ++r) {
                int m = m0 + wm + i * 16 + quad * 4 + r;
                int n = n0 + wn + j * 16 + col;
                out[(size_t)m * EMB + n] = acc[i][j][r] + bias[n];
            }
}

// ---------------- Flash attention: 32x32 MFMA + permlane P-exchange ----------------
// r11: grid 512 -> 1024 (one 128-row q-tile per block). Resources allowed 4
// blocks/CU (VGPR 116, LDS 32KB) but the paired grid capped residency at 2/CU —
// occupancy was grid-limited. qt chosen via nibble-packed perm so every stride-256
// dispatch class sums to 34 k-tiles (load balance across the co-resident grid).
// bh stays in low 6 bits -> same-bh blocks keep their XCD (64 % 8 == 0).
__device__ __forceinline__ void attn_qtile(
    int qt, int b, int h, int lane, int wave,
    const ushort* __restrict__ Qh, const ushort* __restrict__ Kh,
    const ushort* __restrict__ Vh, ushort* __restrict__ Yb,
    ushort* __restrict__ Ks0, ushort* __restrict__ Ks1, ushort* __restrict__ Vs)
{
    const int ql = lane & 31;
    const int hi = lane >> 5;
    const int q0 = qt * 128 + wave * 32;
    const int qrow = q0 + ql;
    const float SC = 0.125f * 1.44269504f;

    bf16x8 qb[4];
    #pragma unroll
    for (int c = 0; c < 4; ++c)
        qb[c] = *(const bf16x8*)(Qh + (size_t)qrow * HDIM + c * 16 + hi * 8);

    f32x16 o2[2] = {};
    float lrun = 0.f;

    const int nk = qt + 1;
    for (int kt = 0; kt < nk; ++kt) {
        const int k0 = kt * 128;
        const bool last = (kt == nk - 1);

        {
            int srow = wave * 16 + (lane >> 2);
            #pragma unroll
            for (int rr = 0; rr < 2; ++rr) {
                int r = rr * 64 + srow;
                int kc = (lane & 3) ^ ((r >> 1) & 3);
                const ushort* src = Kh + (size_t)(k0 + r) * HDIM + kc * 8;
                async_copy16(src,      Ks0 + (rr * 64 + wave * 16) * 32);
                async_copy16(src + 32, Ks1 + (rr * 64 + wave * 16) * 32);
            }
            int kc = (lane & 3) ^ ((srow >> 1) & 3);
            const ushort* vsrc = Vh + (size_t)srow * NTOK + k0 + kc * 8;
            #pragma unroll
            for (int kq = 0; kq < 4; ++kq)
                async_copy16(vsrc + kq * 32, Vs + kq * 2048 + (wave * 16) * 32);
        }
        __syncthreads();

        f32x16 st[4];
        #pragma unroll
        for (int t = 0; t < 4; ++t) {
            f32x16 acc = {};
            #pragma unroll
            for (int c = 0; c < 4; ++c) {
                int row = t * 32 + ql;
                int swz = ((c & 1) * 2 + hi) ^ ((row >> 1) & 3);
                const ushort* Kbase = (c < 2) ? Ks0 : Ks1;
                bf16x8 kf = *(const bf16x8*)&Kbase[row * 32 + swz * 8];
                acc = __builtin_amdgcn_mfma_f32_32x32x16_bf16(kf, qb[c], acc, 0, 0, 0);
            }
            st[t] = acc;
        }

        if (last) {
            #pragma unroll
            for (int t = 0; t < 4; ++t)
                #pragma unroll
                for (int r = 0; r < 16; ++r) {
                    float pv = __builtin_amdgcn_exp2f(st[t][r] * SC);
                    int key = k0 + t * 32 + (r & 3) + 8 * (r >> 2) + 4 * hi;
                    pv = (key <= qrow) ? pv : 0.f;
                    st[t][r] = pv;
                    lrun += pv;
                }
        } else {
            #pragma unroll
            for (int t = 0; t < 4; ++t)
                #pragma unroll
                for (int r = 0; r < 16; ++r) {
                    float pv = __builtin_amdgcn_exp2f(st[t][r] * SC);
                    st[t][r] = pv;
                    lrun += pv;
                }
        }

        #pragma unroll
        for (int t = 0; t < 4; ++t) {
            unsigned int Ap[4], Bp[4];
            #pragma unroll
            for (int m = 0; m < 4; ++m) {
                Ap[m] = cvt2_bf16(st[t][4 * m],     st[t][4 * m + 1]);
                Bp[m] = cvt2_bf16(st[t][4 * m + 2], st[t][4 * m + 3]);
            }
            #pragma unroll
            for (int kc = 0; kc < 2; ++kc) {
                unsigned int xa = Ap[2 * kc], ya = Ap[2 * kc + 1];
                unsigned int xb = Bp[2 * kc], yb = Bp[2 * kc + 1];
                permlane32_swap(xa, ya);
                permlane32_swap(xb, yb);
                u32x4 pw; pw[0] = xa; pw[1] = xb; pw[2] = ya; pw[3] = yb;
                bf16x8 pf = __builtin_bit_cast(bf16x8, pw);
                #pragma unroll
                for (int dt = 0; dt < 2; ++dt) {
                    int row = dt * 32 + ql;
                    int swz = (kc * 2 + hi) ^ ((row >> 1) & 3);
                    bf16x8 vf = *(const bf16x8*)&Vs[t * 2048 + row * 32 + swz * 8];
                    o2[dt] = __builtin_amdgcn_mfma_f32_32x32x16_bf16(vf, pf, o2[dt], 0, 0, 0);
                }
            }
        }
        __syncthreads();
    }

    lrun += __shfl_xor(lrun, 32, 64);
    float inv = 1.f / lrun;
    size_t rbase = ((size_t)(b * SEQ + qrow)) * EMB + h * HDIM;
    #pragma unroll
    for (int dt = 0; dt < 2; ++dt)
        #pragma unroll
        for (int m = 0; m < 4; ++m) {
            int d = dt * 32 + 8 * m + 4 * hi;
            ushort4 s4;
            s4.x = f2bf(o2[dt][4 * m]     * inv);
            s4.y = f2bf(o2[dt][4 * m + 1] * inv);
            s4.z = f2bf(o2[dt][4 * m + 2] * inv);
            s4.w = f2bf(o2[dt][4 * m + 3] * inv);
            *(ushort4*)(Yb + rbase + d) = s4;
        }
}

__global__ __launch_bounds__(256, 2) void attn(
    const ushort* __restrict__ Qb, const ushort* __restrict__ Kb,
    const ushort* __restrict__ Vtx, ushort* __restrict__ Yb)
{
    __shared__ ushort Ks0[128 * 32];   // K d=0..31
    __shared__ ushort Ks1[128 * 32];   // K d=32..63
    __shared__ ushort Vs[4 * 64 * 32]; // V^T key-quarters
    const int lane = threadIdx.x & 63;
    const int wave = threadIdx.x >> 6;
    const int bh   = blockIdx.x & 63;   // b*16+h ; same-bh blocks share an XCD
    const int pr   = blockIdx.x >> 6;   // 16 q-tiles/bh, one per block
    // perm: stride-4 position groups each sum to 34 k-tiles (balanced CU classes)
    const int qt = (int)((0x4567BA983210CDEFULL >> (4 * pr)) & 15);

    const int b = bh >> 4, h = bh & 15;
    const ushort* Qh = Qb + (size_t)bh * SEQ * HDIM;
    const ushort* Kh = Kb + (size_t)bh * SEQ * HDIM;
    const ushort* Vh = Vtx + (size_t)(h * HDIM) * NTOK + b * SEQ;

    attn_qtile(qt, b, h, lane, wave, Qh, Kh, Vh, Yb, Ks0, Ks1, Vs);
}

extern "C" void kernel_launch(void* const* d_in, const int* in_sizes, int n_in,
                              void* d_out, int out_size, void* d_ws, size_t ws_size,
                              hipStream_t stream) {
    const float* x      = (const float*)d_in[0];
    const float* W_qkv  = (const float*)d_in[1];
    const float* b_qkv  = (const float*)d_in[2];
    const float* W_proj = (const float*)d_in[3];
    const float* b_proj = (const float*)d_in[4];
    float* out = (float*)d_out;

    ushort* ws     = (ushort*)d_ws;
    ushort* Xb     = ws;                 // reused as Yb after attn inputs ready
    ushort* Yb     = ws;
    ushort* Wqkvb  = ws + 8388608;
    ushort* Wprojb = ws + 11534336;
    ushort* Qb     = ws + 12582912;
    ushort* Kb     = ws + 20971520;
    ushort* Vtx    = ws + 29360128;      // [1024 channels][8192 tokens]

    hipFuncSetAttribute((const void*)gemm_qk,
                        hipFuncAttributeMaxDynamicSharedMemorySize, 131072);

    cvt_all<<<12288, 256, 0, stream>>>((const float4*)x, (const float4*)W_qkv,
                                       (const float4*)W_proj, Xb, Wqkvb, Wprojb);

    gemm_qk<<<dim3(8, 32), 512, 131072, stream>>>(Xb, Wqkvb, b_qkv, Qb, Kb);
    gemm_vt<<<dim3(8, 64), 256, 0, stream>>>(Wqkvb + (size_t)2048 * EMB, Xb,
                                             b_qkv + 2048, Vtx);
    attn<<<1024, 256, 0, stream>>>(Qb, Kb, Vtx, Yb);
    gemm_proj<<<dim3(64, 8), 256, 0, stream>>>(Yb, Wprojb, b_proj, out);
}